// Round 10
// baseline (3647.191 us; speedup 1.0000x reference)
//
#include <hip/hip_runtime.h>
#include <hip/hip_bf16.h>
#include <math.h>

#define Bb   32
#define Ll   30
#define Hh   300
#define Pp   8
#define Nn   16384
#define Ee   131072
#define NPG  512
#define NI   5

typedef __attribute__((ext_vector_type(4))) float f32x4;
typedef __attribute__((ext_vector_type(8))) short s16x8;

__device__ __forceinline__ float eluf(float x){ return x > 0.f ? x : expm1f(x); }
__device__ __forceinline__ float sigf(float x){ return 1.f/(1.f+expf(-x)); }
__device__ __forceinline__ float wave_sum(float s){
    s += __shfl_xor(s, 32); s += __shfl_xor(s, 16); s += __shfl_xor(s, 8);
    s += __shfl_xor(s, 4);  s += __shfl_xor(s, 2);  s += __shfl_xor(s, 1);
    return s;
}
__device__ __forceinline__ unsigned short f2bf(float x){
    unsigned u = __float_as_uint(x);
    unsigned r = u + 0x7FFFu + ((u >> 16) & 1u);
    return (unsigned short)(r >> 16);
}
__device__ __forceinline__ float bf2f(unsigned short v){
    return __uint_as_float(((unsigned)v) << 16);
}

// ---------------------------------------------------------------------------
// A-tile fetch
// ---------------------------------------------------------------------------
template<int KK, bool BFA>
__device__ __forceinline__ void fetch_as(const float* __restrict__ arowf,
                                         const unsigned short* __restrict__ arowb,
                                         const float* __restrict__ srow,
                                         int k, float* a8, float* s8)
{
    if constexpr (BFA) {
        s16x8 av = *(const s16x8*)(arowb + k);
        float4 w0 = *(const float4*)(srow + k), w1 = *(const float4*)(srow + k + 4);
        s8[0]=w0.x; s8[1]=w0.y; s8[2]=w0.z; s8[3]=w0.w; s8[4]=w1.x; s8[5]=w1.y; s8[6]=w1.z; s8[7]=w1.w;
        #pragma unroll
        for (int j = 0; j < 8; j++) a8[j] = bf2f((unsigned short)av[j]);
    } else {
        if (k + 8 <= KK) {
            float4 v0 = *(const float4*)(arowf + k), v1 = *(const float4*)(arowf + k + 4);
            a8[0]=v0.x; a8[1]=v0.y; a8[2]=v0.z; a8[3]=v0.w; a8[4]=v1.x; a8[5]=v1.y; a8[6]=v1.z; a8[7]=v1.w;
            float4 w0 = *(const float4*)(srow + k), w1 = *(const float4*)(srow + k + 4);
            s8[0]=w0.x; s8[1]=w0.y; s8[2]=w0.z; s8[3]=w0.w; s8[4]=w1.x; s8[5]=w1.y; s8[6]=w1.z; s8[7]=w1.w;
        } else {
            #pragma unroll
            for (int j = 0; j < 8; j++){ int kk = k + j; a8[j] = (kk < KK) ? arowf[kk] : 0.f; s8[j] = (kk < KK) ? srow[kk] : 0.f; }
        }
    }
}

// ---------------------------------------------------------------------------
// MFMA scored-GEMM (round-9 layout: 4 waves = 4 col quarters, 64 rows each)
// ---------------------------------------------------------------------------
template<int KK, int BPITCH, int NTILES, bool BFA>
__device__ __forceinline__ void mfma_score_impl(
    const float* __restrict__ Af, const unsigned short* __restrict__ Ab, int lda,
    const unsigned short* __restrict__ Bt,
    const float* __restrict__ S, int sstride, const int* __restrict__ rowb,
    const float* __restrict__ wpad,
    float* __restrict__ out)
{
    __shared__ unsigned short As[2][64*40];
    __shared__ unsigned short Bs[2][304*40];
    __shared__ float red[4][64];

    const int t = threadIdx.x;
    const int wc = t >> 6, lane = t & 63;
    const int l15 = lane & 15, g = lane >> 4;
    const int rowBlock = blockIdx.x * 64;

    const int sr = t >> 2;
    const int sk = (t & 3) * 8;
    const int grow = rowBlock + sr;
    const int bb = rowb[grow];
    const float* arowf = nullptr;
    const unsigned short* arowb = nullptr;
    if constexpr (BFA) arowb = Ab + (size_t)grow * lda;
    else               arowf = Af + (size_t)grow * lda;
    const float* srow = S + (size_t)bb * sstride;

    f32x4 acc[4][5];
    #pragma unroll
    for (int rt = 0; rt < 4; rt++)
        #pragma unroll
        for (int ct = 0; ct < 5; ct++) acc[rt][ct] = (f32x4){0.f,0.f,0.f,0.f};

    float a8[8], s8[8];
    s16x8 bvec[5];

    {
        fetch_as<KK, BFA>(arowf, arowb, srow, sk, a8, s8);
        #pragma unroll
        for (int i = 0; i < 5; i++){
            int v = t + 256 * i;
            if (v < 1216) bvec[i] = *(const s16x8*)&Bt[(size_t)(v >> 2) * BPITCH + ((v & 3) * 8)];
        }
        s16x8 pv;
        #pragma unroll
        for (int j = 0; j < 8; j++) pv[j] = (short)f2bf(a8[j] * s8[j]);
        *(s16x8*)&As[0][sr * 40 + sk] = pv;
        #pragma unroll
        for (int i = 0; i < 5; i++){
            int v = t + 256 * i;
            if (v < 1216) *(s16x8*)&Bs[0][(v >> 2) * 40 + ((v & 3) * 8)] = bvec[i];
        }
    }
    __syncthreads();

    int cur = 0;
    for (int kt = 0; kt < NTILES; ++kt) {
        if (kt + 1 < NTILES) {
            fetch_as<KK, BFA>(arowf, arowb, srow, (kt + 1) * 32 + sk, a8, s8);
            int k0 = (kt + 1) * 32;
            #pragma unroll
            for (int i = 0; i < 5; i++){
                int v = t + 256 * i;
                if (v < 1216) bvec[i] = *(const s16x8*)&Bt[(size_t)(v >> 2) * BPITCH + k0 + ((v & 3) * 8)];
            }
        }
        s16x8 af[4];
        #pragma unroll
        for (int rt = 0; rt < 4; rt++)
            af[rt] = *(s16x8*)&As[cur][(rt * 16 + l15) * 40 + g * 8];
        #pragma unroll
        for (int ct = 0; ct < 5; ct++) {
            if (wc == 3 && ct == 4) continue;
            int col = wc * 80 + ct * 16 + l15;
            s16x8 bf = *(s16x8*)&Bs[cur][col * 40 + g * 8];
            #pragma unroll
            for (int rt = 0; rt < 4; rt++)
                acc[rt][ct] = __builtin_amdgcn_mfma_f32_16x16x32_bf16(af[rt], bf, acc[rt][ct], 0, 0, 0);
        }
        if (kt + 1 < NTILES) {
            s16x8 pv;
            #pragma unroll
            for (int j = 0; j < 8; j++) pv[j] = (short)f2bf(a8[j] * s8[j]);
            *(s16x8*)&As[cur ^ 1][sr * 40 + sk] = pv;
            #pragma unroll
            for (int i = 0; i < 5; i++){
                int v = t + 256 * i;
                if (v < 1216) *(s16x8*)&Bs[cur ^ 1][(v >> 2) * 40 + ((v & 3) * 8)] = bvec[i];
            }
        }
        __syncthreads();
        cur ^= 1;
    }

    float p[4][4];
    #pragma unroll
    for (int rt = 0; rt < 4; rt++)
        #pragma unroll
        for (int i = 0; i < 4; i++) p[rt][i] = 0.f;
    #pragma unroll
    for (int ct = 0; ct < 5; ct++) {
        if (wc == 3 && ct == 4) continue;
        int col = wc * 80 + ct * 16 + l15;
        float wv = wpad[col];
        #pragma unroll
        for (int rt = 0; rt < 4; rt++)
            #pragma unroll
            for (int i = 0; i < 4; i++)
                p[rt][i] += eluf(acc[rt][ct][i]) * wv;
    }
    #pragma unroll
    for (int m = 1; m <= 8; m <<= 1) {
        #pragma unroll
        for (int rt = 0; rt < 4; rt++)
            #pragma unroll
            for (int i = 0; i < 4; i++)
                p[rt][i] += __shfl_xor(p[rt][i], m);
    }
    if (l15 == 0) {
        #pragma unroll
        for (int rt = 0; rt < 4; rt++)
            #pragma unroll
            for (int i = 0; i < 4; i++)
                red[wc][rt * 16 + g * 4 + i] = p[rt][i];
    }
    __syncthreads();
    if (t < 64)
        out[rowBlock + t] = red[0][t] + red[1][t] + red[2][t] + red[3][t];
}

__global__ __launch_bounds__(256, 2) void mfma_node_k(
    const unsigned short* __restrict__ Ab, const unsigned short* __restrict__ Bt,
    const float* __restrict__ S, const int* __restrict__ rowb,
    const float* __restrict__ wpad, float* __restrict__ out)
{
    mfma_score_impl<2400, 2400, 75, true>(nullptr, Ab, 2400, Bt, S, 2400, rowb, wpad, out);
}
__global__ __launch_bounds__(256, 2) void mfma_edge_k(
    const unsigned short* __restrict__ Ab, const unsigned short* __restrict__ Bt,
    const float* __restrict__ S, const int* __restrict__ rowb,
    const float* __restrict__ wpad, float* __restrict__ out)
{
    mfma_score_impl<320, 320, 10, true>(nullptr, Ab, 320, Bt, S, NI * 300, rowb, wpad, out);
}
__global__ __launch_bounds__(256, 2) void mfma_node_f_k(
    const float* __restrict__ A, const unsigned short* __restrict__ Bt,
    const float* __restrict__ S, const int* __restrict__ rowb,
    const float* __restrict__ wpad, float* __restrict__ out)
{
    mfma_score_impl<2400, 2400, 75, false>(A, nullptr, 2400, Bt, S, 2400, rowb, wpad, out);
}
__global__ __launch_bounds__(256, 2) void mfma_edge_f_k(
    const float* __restrict__ A, const unsigned short* __restrict__ Bt,
    const float* __restrict__ S, const int* __restrict__ rowb,
    const float* __restrict__ wpad, float* __restrict__ out)
{
    mfma_score_impl<300, 320, 10, false>(A, nullptr, 300, Bt, S, NI * 300, rowb, wpad, out);
}

// ---------------------------------------------------------------------------
// Generic MFMA GEMM. Optional fused add: C += simlast[row*2001] * qm[row*300+col]
// ---------------------------------------------------------------------------
__global__ __launch_bounds__(256, 2) void mfma_gemm_k(
    const float* __restrict__ A, int lda, int K, int ntiles,
    const unsigned short* __restrict__ Bt, int bpitch,
    int ncols, float* __restrict__ C, int ldc,
    const float* __restrict__ simlast, const float* __restrict__ qm)
{
    __shared__ unsigned short As[2][64*40];
    __shared__ unsigned short Bs[2][304*40];

    const int t = threadIdx.x;
    const int wc = t >> 6, lane = t & 63;
    const int l15 = lane & 15, g = lane >> 4;
    const int rowBlock = blockIdx.x * 64;
    const int colBlock = blockIdx.y * 304;

    const int sr = t >> 2, sk = (t & 3) * 8;
    const float* arow = A + (size_t)(rowBlock + sr) * lda;

    f32x4 acc[4][5];
    #pragma unroll
    for (int rt = 0; rt < 4; rt++)
        #pragma unroll
        for (int ct = 0; ct < 5; ct++) acc[rt][ct] = (f32x4){0.f,0.f,0.f,0.f};

    float a8[8];
    s16x8 bvec[5];

    {
        int k = sk;
        if (k + 8 <= K) {
            float4 v0 = *(const float4*)(arow + k), v1 = *(const float4*)(arow + k + 4);
            a8[0]=v0.x; a8[1]=v0.y; a8[2]=v0.z; a8[3]=v0.w; a8[4]=v1.x; a8[5]=v1.y; a8[6]=v1.z; a8[7]=v1.w;
        } else {
            #pragma unroll
            for (int j = 0; j < 8; j++){ int kk = k + j; a8[j] = (kk < K) ? arow[kk] : 0.f; }
        }
        #pragma unroll
        for (int i = 0; i < 5; i++){
            int v = t + 256 * i;
            if (v < 1216) bvec[i] = *(const s16x8*)&Bt[(size_t)(colBlock + (v >> 2)) * bpitch + ((v & 3) * 8)];
        }
        s16x8 pv;
        #pragma unroll
        for (int j = 0; j < 8; j++) pv[j] = (short)f2bf(a8[j]);
        *(s16x8*)&As[0][sr * 40 + sk] = pv;
        #pragma unroll
        for (int i = 0; i < 5; i++){
            int v = t + 256 * i;
            if (v < 1216) *(s16x8*)&Bs[0][(v >> 2) * 40 + ((v & 3) * 8)] = bvec[i];
        }
    }
    __syncthreads();

    int cur = 0;
    for (int kt = 0; kt < ntiles; ++kt) {
        if (kt + 1 < ntiles) {
            int k = (kt + 1) * 32 + sk;
            if (k + 8 <= K) {
                float4 v0 = *(const float4*)(arow + k), v1 = *(const float4*)(arow + k + 4);
                a8[0]=v0.x; a8[1]=v0.y; a8[2]=v0.z; a8[3]=v0.w; a8[4]=v1.x; a8[5]=v1.y; a8[6]=v1.z; a8[7]=v1.w;
            } else {
                #pragma unroll
                for (int j = 0; j < 8; j++){ int kk = k + j; a8[j] = (kk < K) ? arow[kk] : 0.f; }
            }
            int k0 = (kt + 1) * 32;
            #pragma unroll
            for (int i = 0; i < 5; i++){
                int v = t + 256 * i;
                if (v < 1216) bvec[i] = *(const s16x8*)&Bt[(size_t)(colBlock + (v >> 2)) * bpitch + k0 + ((v & 3) * 8)];
            }
        }
        s16x8 af[4];
        #pragma unroll
        for (int rt = 0; rt < 4; rt++)
            af[rt] = *(s16x8*)&As[cur][(rt * 16 + l15) * 40 + g * 8];
        #pragma unroll
        for (int ct = 0; ct < 5; ct++) {
            if (wc == 3 && ct == 4) continue;
            int col = wc * 80 + ct * 16 + l15;
            s16x8 bf = *(s16x8*)&Bs[cur][col * 40 + g * 8];
            #pragma unroll
            for (int rt = 0; rt < 4; rt++)
                acc[rt][ct] = __builtin_amdgcn_mfma_f32_16x16x32_bf16(af[rt], bf, acc[rt][ct], 0, 0, 0);
        }
        if (kt + 1 < ntiles) {
            s16x8 pv;
            #pragma unroll
            for (int j = 0; j < 8; j++) pv[j] = (short)f2bf(a8[j]);
            *(s16x8*)&As[cur ^ 1][sr * 40 + sk] = pv;
            #pragma unroll
            for (int i = 0; i < 5; i++){
                int v = t + 256 * i;
                if (v < 1216) *(s16x8*)&Bs[cur ^ 1][(v >> 2) * 40 + ((v & 3) * 8)] = bvec[i];
            }
        }
        __syncthreads();
        cur ^= 1;
    }

    #pragma unroll
    for (int ct = 0; ct < 5; ct++) {
        if (wc == 3 && ct == 4) continue;
        int col = colBlock + wc * 80 + ct * 16 + l15;
        if (col >= ncols) continue;
        #pragma unroll
        for (int rt = 0; rt < 4; rt++) {
            int row0 = rowBlock + rt * 16 + g * 4;
            #pragma unroll
            for (int i = 0; i < 4; i++) {
                float v = acc[rt][ct][i];
                int row = row0 + i;
                if (simlast) v += simlast[(size_t)row * 2001] * qm[(size_t)row * 300 + col];
                C[(size_t)row * ldc + col] = v;
            }
        }
    }
}

// ---------------------------------------------------------------------------
// Builders
// ---------------------------------------------------------------------------
__global__ void build_btg_k(const float* __restrict__ B, int K, int N,
                            int ncpad, int pitch, unsigned short* __restrict__ Bt)
{
    int idx = blockIdx.x * 256 + threadIdx.x;
    if (idx >= ncpad * pitch) return;
    int col = idx / pitch, k = idx - col * pitch;
    float v = (col < N && k < K) ? B[(size_t)k * N + col] : 0.f;
    Bt[idx] = f2bf(v);
}
__global__ void build_vocab_bt_k(const float* __restrict__ cv, const float* __restrict__ td,
                                 unsigned short* __restrict__ Bt)
{
    int idx = blockIdx.x * 256 + threadIdx.x;
    if (idx >= 2128 * 320) return;
    int col = idx / 320, k = idx - col * 320;
    float v = 0.f;
    if (k < 300) {
        if (col < 2000) v = cv[(size_t)col * 300 + k];
        else if (col == 2000) v = td[k];
    }
    Bt[idx] = f2bf(v);
}
// lstm Wih as B^T with interleaved gate cols: col' = 4u+gt -> src row gt*300+u.
// Table [1520][320].
__global__ void build_btw2_k(const float* __restrict__ Wih, unsigned short* __restrict__ Bt)
{
    int idx = blockIdx.x * 256 + threadIdx.x;
    if (idx >= 1520 * 320) return;
    int col = idx / 320, k = idx - col * 320;
    float v = 0.f;
    if (col < 1280 && k < 300) {
        int u = col >> 2, gt = col & 3;
        if (u < 300) v = Wih[(size_t)(gt * 300 + u) * 300 + k];
    }
    Bt[idx] = f2bf(v);
}
// Whh fragment-major table: fragB[(ctg*10+ks)*512 + lane*8 + j], ctg<80
__global__ void build_fragB_k(const float* __restrict__ Whh, unsigned short* __restrict__ FB)
{
    int idx = blockIdx.x * 256 + threadIdx.x;
    if (idx >= 80 * 10 * 512) return;
    int j = idx & 7;
    int lane = (idx >> 3) & 63;
    int ks = (idx >> 9) % 10;
    int ctg = idx / 5120;
    int col = ctg * 16 + (lane & 15);
    int k = ks * 32 + (lane >> 4) * 8 + j;
    float v = 0.f;
    int u = col >> 2, gt = col & 3;
    if (u < 300 && k < 300) v = Whh[(size_t)(gt * 300 + u) * 300 + k];
    FB[idx] = f2bf(v);
}
__global__ void build_bias2_k(const float* __restrict__ bih, const float* __restrict__ bhh,
                              float* __restrict__ b2)
{
    int col = blockIdx.x * 256 + threadIdx.x;
    if (col >= 1280) return;
    int u = col >> 2, gt = col & 3;
    b2[col] = (u < 300) ? (bih[gt * 300 + u] + bhh[gt * 300 + u]) : 0.f;
}

__global__ void cvt_attr8_k(const float* __restrict__ src, long rows, int K, int pitch,
                            unsigned short* __restrict__ dst)
{
    const int pg = pitch >> 3;
    long total = rows * pg;
    for (long i = (long)blockIdx.x * blockDim.x + threadIdx.x; i < total;
         i += (long)gridDim.x * blockDim.x) {
        long r = i / pg;
        int kg = (int)(i - r * pg) * 8;
        s16x8 v;
        #pragma unroll
        for (int j = 0; j < 8; j++){
            int k = kg + j;
            float x = (k < K) ? src[r * (long)K + k] : 0.f;
            v[j] = (short)f2bf(x);
        }
        *(s16x8*)&dst[r * (long)pitch + kg] = v;
    }
}

__global__ void wpad_k(const float* __restrict__ wn, const float* __restrict__ wr,
                       float* __restrict__ wnp, float* __restrict__ wrp)
{
    int i = threadIdx.x;
    if (i < 304) { wnp[i] = (i < 300) ? wn[i] : 0.f; wrp[i] = (i < 300) ? wr[i] : 0.f; }
}

__global__ void transpose_k(const float* __restrict__ src, int R, int C,
                            float* __restrict__ dst)
{
    int idx = blockIdx.x * 256 + threadIdx.x;
    if (idx >= R * C) return;
    int r = idx / C, c = idx - r * C;
    dst[(size_t)c * R + r] = src[idx];
}

// ---------------------------------------------------------------------------
__global__ void softmax_rows_k(float* __restrict__ X, int nc)
{
    int row = blockIdx.x, t = threadIdx.x;
    __shared__ float red[256];
    size_t base = (size_t)row * nc;
    float m = -3.4e38f;
    for (int i = t; i < nc; i += 256) m = fmaxf(m, X[base + i]);
    red[t] = m; __syncthreads();
    for (int s = 128; s > 0; s >>= 1){ if (t < s) red[t] = fmaxf(red[t], red[t+s]); __syncthreads(); }
    float mx = red[0]; __syncthreads();
    float sm = 0.f;
    for (int i = t; i < nc; i += 256){ float e = expf(X[base + i] - mx); X[base + i] = e; sm += e; }
    red[t] = sm; __syncthreads();
    for (int s = 128; s > 0; s >>= 1){ if (t < s) red[t] += red[t+s]; __syncthreads(); }
    float inv = 1.f / red[0];
    for (int i = t; i < nc; i += 256) X[base + i] *= inv;
}

// ---------------------------------------------------------------------------
// Single-block MFMA LSTM: all 32 batches, gates via h[32x300]@Whh^T per step.
// Gate cols interleaved: col' = 4u + {i,f,g,o}. h kept bf16 in LDS (A layout).
// xw2: [960][1280] (reordered cols). fragB: fragment-major Whh. bias2: [1280].
// ---------------------------------------------------------------------------
__global__ __launch_bounds__(1024) void lstm_mfma_k(
    const float* __restrict__ xw2, const unsigned short* __restrict__ fragB,
    const float* __restrict__ bias2, const int* __restrict__ lengths,
    float* __restrict__ encoded)
{
    __shared__ unsigned short h_bf[32 * 320];   // 20 KB, [batch][k] bf16
    __shared__ float gates[32 * 648];           // 83 KB, one half: [batch][640 local cols]
    __shared__ int maxlen_s;

    const int t = threadIdx.x;
    const int w = t >> 6, lane = t & 63;
    const int l15 = lane & 15, g = lane >> 4;

    for (int i = t; i < 32 * 320; i += 1024) h_bf[i] = 0;
    if (t == 0) {
        int m = 0;
        for (int b2 = 0; b2 < Bb; b2++) m = max(m, lengths[b2]);
        maxlen_s = m;
    }

    // pair ownership: p = t + 1024*s, p = b*300+u
    float creg[10], hreg[10];
    int myb[10], myu[10], mylen[10];
    #pragma unroll
    for (int s = 0; s < 10; s++) {
        creg[s] = 0.f; hreg[s] = 0.f;
        int p = t + 1024 * s;
        if (p < 9600) { myb[s] = p / 300; myu[s] = p - myb[s] * 300; mylen[s] = lengths[myb[s]]; }
        else myb[s] = -1;
    }
    __syncthreads();
    const int maxlen = maxlen_s;

    for (int st = 0; st < maxlen; ++st) {
        #pragma unroll
        for (int half = 0; half < 2; ++half) {
            // MFMA: wave w owns col tiles {w, w+16, w+32} < 40 of this half
            f32x4 acc[2][3];
            #pragma unroll
            for (int rt = 0; rt < 2; rt++)
                #pragma unroll
                for (int ci = 0; ci < 3; ci++) acc[rt][ci] = (f32x4){0.f,0.f,0.f,0.f};
            #pragma unroll
            for (int ci = 0; ci < 3; ci++) {
                int ct = w + 16 * ci;
                if (ct >= 40) continue;
                int ctg = half * 40 + ct;
                #pragma unroll
                for (int ks = 0; ks < 10; ks++) {
                    s16x8 bf = *(const s16x8*)&fragB[((size_t)(ctg * 10 + ks)) * 512 + lane * 8];
                    s16x8 af0 = *(s16x8*)&h_bf[(l15) * 320 + ks * 32 + g * 8];
                    s16x8 af1 = *(s16x8*)&h_bf[(16 + l15) * 320 + ks * 32 + g * 8];
                    acc[0][ci] = __builtin_amdgcn_mfma_f32_16x16x32_bf16(af0, bf, acc[0][ci], 0, 0, 0);
                    acc[1][ci] = __builtin_amdgcn_mfma_f32_16x16x32_bf16(af1, bf, acc[1][ci], 0, 0, 0);
                }
            }
            // write gates (C: col=l15, row=g*4+i per 16-row tile)
            #pragma unroll
            for (int ci = 0; ci < 3; ci++) {
                int ct = w + 16 * ci;
                if (ct >= 40) continue;
                #pragma unroll
                for (int rt = 0; rt < 2; rt++)
                    #pragma unroll
                    for (int i = 0; i < 4; i++)
                        gates[(rt * 16 + g * 4 + i) * 648 + ct * 16 + l15] = acc[rt][ci][i];
            }
            __syncthreads();
            // activation for units in [half*160, half*160+160)
            const int ulo = half * 160;
            #pragma unroll
            for (int s = 0; s < 10; s++) {
                if (myb[s] < 0) continue;
                int u = myu[s];
                if (u < ulo || u >= ulo + 160) continue;
                if (st >= mylen[s]) continue;
                int lc = (u - ulo) * 4;
                float4 gv = *(float4*)&gates[myb[s] * 648 + lc];
                float4 bv = *(const float4*)&bias2[half * 640 + lc];
                float4 xv = *(const float4*)&xw2[(size_t)(myb[s] * Ll + st) * 1280 + half * 640 + lc];
                float i_ = sigf (gv.x + bv.x + xv.x);
                float f_ = sigf (gv.y + bv.y + xv.y);
                float g_ = tanhf(gv.z + bv.z + xv.z);
                float o_ = sigf (gv.w + bv.w + xv.w);
                creg[s] = f_ * creg[s] + i_ * g_;
                hreg[s] = o_ * tanhf(creg[s]);
            }
            __syncthreads();
        }
        // publish h for next step
        #pragma unroll
        for (int s = 0; s < 10; s++)
            if (myb[s] >= 0) h_bf[myb[s] * 320 + myu[s]] = f2bf(hreg[s]);
        __syncthreads();
    }
    #pragma unroll
    for (int s = 0; s < 10; s++)
        if (myb[s] >= 0) encoded[myb[s] * 300 + myu[s]] = hreg[s];
}

// Persistent RNN decoder
__global__ __launch_bounds__(320) void rnn_all_k(
    const float* __restrict__ enc, const float* __restrict__ WihT,
    const float* __restrict__ WhhT,
    const float* __restrict__ bih, const float* __restrict__ bhh,
    float* __restrict__ hidden)
{
    __shared__ float es[304];
    __shared__ float hs[304];
    const int b = blockIdx.x, i = threadIdx.x;
    const bool act = i < 300;
    if (act) { es[i] = enc[b * 300 + i]; hs[i] = 0.f; }
    __syncthreads();
    float ex = 0.f;
    if (act) {
        #pragma unroll 8
        for (int k = 0; k < 300; k++)
            ex = fmaf(es[k], WihT[(size_t)k * 300 + i], ex);
        ex += bih[i] + bhh[i];
    }
    for (int it = 0; it < NI; it++) {
        __syncthreads();
        float d = 0.f;
        if (act) {
            #pragma unroll 8
            for (int k = 0; k < 300; k++)
                d = fmaf(hs[k], WhhT[(size_t)k * 300 + i], d);
        }
        float v = fmaxf(ex + d, 0.f);
        __syncthreads();
        if (act) { hs[i] = v; hidden[((size_t)b * NI + it) * 300 + i] = v; }
    }
}

__global__ __launch_bounds__(256) void scores_instr_k(
    const float* __restrict__ hidden, const float* __restrict__ tagged,
    const int* __restrict__ lengths, float* __restrict__ instr)
{
    __shared__ float sc[4][32];
    int wv = threadIdx.x >> 6;
    int wid = blockIdx.x * 4 + wv;
    int lane = threadIdx.x & 63;
    int b = wid / NI;
    const float* hr = hidden + (size_t)wid * Hh;
    float hv[5];
    #pragma unroll
    for (int p = 0; p < 5; p++){ int k = lane + p * 64; hv[p] = (k < Hh) ? hr[k] : 0.f; }
    int len = lengths[b];
    for (int l = 0; l < Ll; l++){
        const float* trw = tagged + ((size_t)b * Ll + l) * Hh;
        float s = 0.f;
        #pragma unroll
        for (int p = 0; p < 5; p++){ int k = lane + p * 64; if (k < Hh) s += hv[p] * trw[k]; }
        s = wave_sum(s);
        if (lane == 0) sc[wv][l] = s;
    }
    __syncthreads();
    float mx = -3.4e38f;
    for (int l = 0; l < len; l++) mx = fmaxf(mx, sc[wv][l]);
    float sum = 0.f;
    for (int l = 0; l < len; l++) sum += expf(sc[wv][l] - mx);
    float inv = 1.f / sum;
    float a[5] = {0.f,0.f,0.f,0.f,0.f};
    for (int l = 0; l < len; l++){
        float pl = expf(sc[wv][l] - mx) * inv;
        const float* trw = tagged + ((size_t)b * Ll + l) * Hh;
        #pragma unroll
        for (int p = 0; p < 5; p++){ int k = lane + p * 64; if (k < Hh) a[p] += pl * trw[k]; }
    }
    #pragma unroll
    for (int p = 0; p < 5; p++){ int k = lane + p * 64; if (k < Hh) instr[(size_t)wid * Hh + k] = a[p]; }
}

__global__ __launch_bounds__(256) void prop_softmax_all_k(
    const float* __restrict__ instr, const float* __restrict__ pemb,
    float* __restrict__ psim5, float* __restrict__ rsim5)
{
    int wid = blockIdx.x * 4 + (threadIdx.x >> 6);
    int lane = threadIdx.x & 63;
    const float* ir = instr + (size_t)wid * Hh;
    float iv[5];
    #pragma unroll
    for (int p = 0; p < 5; p++){ int k = lane + p * 64; iv[p] = (k < Hh) ? ir[k] : 0.f; }
    float e[9];
    #pragma unroll
    for (int j = 0; j < 9; j++){
        const float* pr = pemb + j * Hh;
        float s = 0.f;
        #pragma unroll
        for (int p = 0; p < 5; p++){ int k = lane + p * 64; if (k < Hh) s += iv[p] * pr[k]; }
        e[j] = wave_sum(s);
    }
    if (lane == 0){
        float mx = e[0];
        #pragma unroll
        for (int j = 1; j < 9; j++) mx = fmaxf(mx, e[j]);
        float sum = 0.f;
        #pragma unroll
        for (int j = 0; j < 9; j++){ e[j] = expf(e[j] - mx); sum += e[j]; }
        float inv = 1.f / sum;
        #pragma unroll
        for (int p = 0; p < 8; p++) psim5[wid * 8 + p] = e[p] * inv;
        rsim5[wid] = e[8] * inv;
    }
}

__global__ void iscale4_k(const float* __restrict__ instr,
                          const float* __restrict__ psim5, float* __restrict__ iscale4)
{
    int idx = blockIdx.x * 256 + threadIdx.x;
    if (idx >= 4 * Bb * 2400) return;
    int step = idx / (Bb * 2400);
    int r = idx - step * (Bb * 2400);
    int b = r / 2400; int k = r - b * 2400;
    int p = k / 300;  int h = k - p * 300;
    iscale4[idx] = instr[((size_t)b * NI + step) * Hh + h] * psim5[(b * NI + step) * 8 + p];
}

// ---------------------------------------------------------------------------
// Fused message-passing tail: one block per graph, 4 steps internal, LDS state.
// Graph structure guarantees: node_indices[n] = n/512, edges stay within graph.
// ---------------------------------------------------------------------------
__global__ __launch_bounds__(512) void msg_tail_k(
    const int* __restrict__ ei, const int* __restrict__ eb,
    const float* __restrict__ es4, const float* __restrict__ nsc4,
    const float* __restrict__ rsim5, float* __restrict__ dist_out)
{
    __shared__ float dist[NPG];
    __shared__ float msg[NPG];
    __shared__ float red[512];
    const int b = blockIdx.x, t = threadIdx.x;
    dist[t] = 1.f / (float)NPG;
    msg[t] = 0.f;
    __syncthreads();
    for (int step = 0; step < 4; ++step) {
        const float* es = es4 + (size_t)step * Ee;
        for (int i = t; i < Ee; i += 512) {
            if (eb[i] == b) {
                int s = ei[i] - b * NPG;
                int d = ei[Ee + i] - b * NPG;
                atomicAdd(&msg[d], dist[s] * es[i]);
            }
        }
        __syncthreads();
        float a = nsc4[(size_t)step * Nn + b * NPG + t];
        float m = msg[t];
        red[t] = a; __syncthreads();
        for (int s2 = 256; s2 > 0; s2 >>= 1){ if (t < s2) red[t] = fmaxf(red[t], red[t+s2]); __syncthreads(); }
        float mN = red[0]; __syncthreads();
        float ea = expf(a - mN);
        red[t] = ea; __syncthreads();
        for (int s2 = 256; s2 > 0; s2 >>= 1){ if (t < s2) red[t] += red[t+s2]; __syncthreads(); }
        float sN = red[0]; __syncthreads();
        red[t] = m; __syncthreads();
        for (int s2 = 256; s2 > 0; s2 >>= 1){ if (t < s2) red[t] = fmaxf(red[t], red[t+s2]); __syncthreads(); }
        float mM = red[0]; __syncthreads();
        float em = expf(m - mM);
        red[t] = em; __syncthreads();
        for (int s2 = 256; s2 > 0; s2 >>= 1){ if (t < s2) red[t] += red[t+s2]; __syncthreads(); }
        float sM = red[0]; __syncthreads();
        float rs = rsim5[b * NI + step];
        dist[t] = rs * (em / sM) + (1.f - rs) * (ea / sN);
        msg[t] = 0.f;
        __syncthreads();
    }
    dist_out[b * NPG + t] = dist[t];
}

// final aggregation (bf16 attrs)
__global__ __launch_bounds__(320) void final_agg_bf_k(
    const float* __restrict__ psim5, const float* __restrict__ dist,
    const unsigned short* __restrict__ nab, float* __restrict__ agg)
{
    int chunk = blockIdx.x;
    int b = blockIdx.y;
    int h = threadIdx.x;
    if (h >= Hh) return;
    float ps[8];
    #pragma unroll
    for (int p = 0; p < 8; p++) ps[p] = psim5[(b * NI + 4) * 8 + p];
    float acc = 0.f;
    for (int i = 0; i < 32; i++){
        int n = b * NPG + chunk * 32 + i;
        const unsigned short* row = nab + (size_t)n * 2400;
        float wsum = 0.f;
        #pragma unroll
        for (int p = 0; p < 8; p++) wsum += ps[p] * bf2f(row[p * Hh + h]);
        acc += dist[n] * wsum;
    }
    atomicAdd(&agg[b * Hh + h], acc);
}
__global__ __launch_bounds__(320) void final_agg_k(
    const float* __restrict__ psim5, const float* __restrict__ dist,
    const float* __restrict__ na, float* __restrict__ agg)
{
    int chunk = blockIdx.x;
    int b = blockIdx.y;
    int h = threadIdx.x;
    if (h >= Hh) return;
    float ps[8];
    #pragma unroll
    for (int p = 0; p < 8; p++) ps[p] = psim5[(b * NI + 4) * 8 + p];
    float acc = 0.f;
    for (int i = 0; i < 32; i++){
        int n = b * NPG + chunk * 32 + i;
        const float* row = na + (size_t)n * Pp * Hh;
        float wsum = 0.f;
        #pragma unroll
        for (int p = 0; p < 8; p++) wsum += ps[p] * row[p * Hh + h];
        acc += dist[n] * wsum;
    }
    atomicAdd(&agg[b * Hh + h], acc);
}

// fc1 with fused feats (reads enc | agg directly), elu epilogue
__global__ void fc1_k(const float* __restrict__ enc, const float* __restrict__ agg,
                      const float* __restrict__ W, const float* __restrict__ bias,
                      float* __restrict__ z)
{
    int idx = blockIdx.x * 256 + threadIdx.x;
    if (idx >= Bb * 600) return;
    int m = idx / 600, j = idx - m * 600;
    const float* wr = W + (size_t)j * 600;
    float s = 0.f;
    for (int k = 0; k < 300; k++) s += enc[m * 300 + k] * wr[k];
    for (int k = 0; k < 300; k++) s += agg[m * 300 + k] * wr[300 + k];
    z[idx] = eluf(s + bias[j]);
}

__global__ void fc2_k(const float* __restrict__ z, const float* __restrict__ W,
                      const float* __restrict__ bias, float* __restrict__ out)
{
    int idx = blockIdx.x * 256 + threadIdx.x;
    if (idx >= Bb * 1845) return;
    int m = idx / 1845, j = idx - m * 1845;
    const float* wr = W + (size_t)j * 600;
    const float* zr = z + m * 600;
    float s = 0.f;
    for (int k = 0; k < 600; k++) s += zr[k] * wr[k];
    out[idx] = s + bias[j];
}

// ---------------------------------------------------------------------------
extern "C" void kernel_launch(void* const* d_in, const int* in_sizes, int n_in,
                              void* d_out, int out_size, void* d_ws, size_t ws_size,
                              hipStream_t stream)
{
    const float* questions      = (const float*)d_in[0];
    const int*   lengths        = (const int*)  d_in[1];
    const int*   node_indices   = (const int*)  d_in[2];
    const int*   edge_indices   = (const int*)  d_in[3];
    const int*   edge_batch     = (const int*)  d_in[4];
    const float* node_attrs     = (const float*)d_in[5];
    const float* edge_attrs     = (const float*)d_in[6];
    const float* concept_vocab  = (const float*)d_in[7];
    const float* prop_emb       = (const float*)d_in[8];
    const float* tagger_default = (const float*)d_in[9];
    const float* tagger_weight  = (const float*)d_in[10];
    const float* lstm_Wih       = (const float*)d_in[11];
    const float* lstm_Whh       = (const float*)d_in[12];
    const float* lstm_bih       = (const float*)d_in[13];
    const float* lstm_bhh       = (const float*)d_in[14];
    const float* rnn_Wih        = (const float*)d_in[15];
    const float* rnn_Whh        = (const float*)d_in[16];
    const float* rnn_bih        = (const float*)d_in[17];
    const float* rnn_bhh        = (const float*)d_in[18];
    const float* Wnp            = (const float*)d_in[19];
    const float* Wedge          = (const float*)d_in[20];
    const float* w_nscore       = (const float*)d_in[21];
    const float* w_rscore       = (const float*)d_in[22];
    const float* fc1_W          = (const float*)d_in[23];
    const float* fc1_b          = (const float*)d_in[24];
    const float* fc2_W          = (const float*)d_in[25];
    const float* fc2_b          = (const float*)d_in[26];
    float* outf = (float*)d_out;

    float* ws = (float*)d_ws;
    size_t off = 0;
    auto alloc = [&](size_t n){ size_t r = off; off += (n + 63) & ~(size_t)63; return r; };
    size_t o_q2     = alloc(960 * 300);
    size_t o_sim    = alloc((size_t)960 * 2001);
    size_t o_tagged = alloc(960 * 300);
    size_t o_xw     = alloc((size_t)960 * 1280);
    size_t o_enc    = alloc(9600);
    size_t o_hidden = alloc(48000);
    size_t o_instr  = alloc(48000);
    size_t o_psim5  = alloc(1280);
    size_t o_rsim5  = alloc(160);
    size_t o_iscl4  = alloc((size_t)4 * Bb * 2400);
    size_t o_nsc4   = alloc((size_t)4 * Nn);
    size_t o_es4    = alloc((size_t)4 * Ee);
    size_t o_dist   = alloc(Nn);
    size_t o_agg    = alloc(9600);
    size_t o_z      = alloc(19200);
    size_t o_btn    = alloc((size_t)304 * 2400 / 2);
    size_t o_bte    = alloc((size_t)304 * 320 / 2);
    size_t o_wn     = alloc(304);
    size_t o_wr     = alloc(304);
    size_t o_rwhhT  = alloc(90000);
    size_t o_rwihT  = alloc(90000);
    size_t o_btq    = alloc((size_t)304 * 320 / 2);
    size_t o_btv    = alloc((size_t)2128 * 320 / 2);
    size_t o_btc    = alloc((size_t)304 * 2016 / 2);
    size_t o_btw2   = alloc((size_t)1520 * 320 / 2);   // lstm Wih interleaved B^T
    size_t o_fragB  = alloc((size_t)80 * 10 * 512 / 2);// lstm Whh fragment-major
    size_t o_bias2  = alloc(1280);
    size_t o_nab    = alloc((size_t)Nn * 2400 / 2);
    size_t o_eab    = alloc((size_t)Ee * 320 / 2);
    const bool bigws = ws_size >= off * sizeof(float);

    unsigned short* btn = (unsigned short*)(ws + o_btn);
    unsigned short* bte = (unsigned short*)(ws + o_bte);
    unsigned short* btq = (unsigned short*)(ws + o_btq);
    unsigned short* btv = (unsigned short*)(ws + o_btv);
    unsigned short* btc = (unsigned short*)(ws + o_btc);
    unsigned short* btw2 = (unsigned short*)(ws + o_btw2);
    unsigned short* fragB = (unsigned short*)(ws + o_fragB);
    unsigned short* nab = (unsigned short*)(ws + o_nab);
    unsigned short* eab = (unsigned short*)(ws + o_eab);

    // ---- one-time conversions ----
    build_btg_k<<<(304*2400 + 255)/256, 256, 0, stream>>>(Wnp, 2400, 300, 304, 2400, btn);
    build_btg_k<<<(304*320 + 255)/256, 256, 0, stream>>>(Wedge, 300, 300, 304, 320, bte);
    wpad_k<<<1, 320, 0, stream>>>(w_nscore, w_rscore, ws + o_wn, ws + o_wr);
    transpose_k<<<(300*300 + 255)/256, 256, 0, stream>>>(rnn_Whh, 300, 300, ws + o_rwhhT);
    transpose_k<<<(300*300 + 255)/256, 256, 0, stream>>>(rnn_Wih, 300, 300, ws + o_rwihT);
    build_btg_k<<<(304*320 + 255)/256, 256, 0, stream>>>(tagger_weight, 300, 300, 304, 320, btq);
    build_vocab_bt_k<<<(2128*320 + 255)/256, 256, 0, stream>>>(concept_vocab, tagger_default, btv);
    build_btg_k<<<(304*2016 + 255)/256, 256, 0, stream>>>(concept_vocab, 2000, 300, 304, 2016, btc);
    build_btw2_k<<<(1520*320 + 255)/256, 256, 0, stream>>>(lstm_Wih, btw2);
    build_fragB_k<<<(80*10*512 + 255)/256, 256, 0, stream>>>(lstm_Whh, fragB);
    build_bias2_k<<<5, 256, 0, stream>>>(lstm_bih, lstm_bhh, ws + o_bias2);
    if (bigws) {
        cvt_attr8_k<<<2048, 256, 0, stream>>>(node_attrs, Nn, 2400, 2400, nab);
        cvt_attr8_k<<<2048, 256, 0, stream>>>(edge_attrs, Ee, 300, 320, eab);
    }

    // ---- tagger chain ----
    mfma_gemm_k<<<dim3(15,1), 256, 0, stream>>>(
        questions, 300, 300, 10, btq, 320, 300, ws + o_q2, 300, nullptr, nullptr);
    mfma_gemm_k<<<dim3(15,7), 256, 0, stream>>>(
        ws + o_q2, 300, 300, 10, btv, 320, 2001, ws + o_sim, 2001, nullptr, nullptr);
    softmax_rows_k<<<960, 256, 0, stream>>>(ws + o_sim, 2001);
    // tagged = sim[:, :2000] @ concept_vocab  (+ fused sim[:,2000]*questions)
    mfma_gemm_k<<<dim3(15,1), 256, 0, stream>>>(
        ws + o_sim, 2001, 2000, 63, btc, 2016, 300, ws + o_tagged, 300,
        ws + o_sim + 2000, questions);

    // ---- LSTM ----
    mfma_gemm_k<<<dim3(15,5), 256, 0, stream>>>(
        ws + o_tagged, 300, 300, 10, btw2, 320, 1280, ws + o_xw, 1280, nullptr, nullptr);
    lstm_mfma_k<<<1, 1024, 0, stream>>>(ws + o_xw, fragB, ws + o_bias2, lengths, ws + o_enc);

    // ---- RNN + instructions ----
    rnn_all_k<<<Bb, 320, 0, stream>>>(ws + o_enc, ws + o_rwihT, ws + o_rwhhT,
                                      rnn_bih, rnn_bhh, ws + o_hidden);
    scores_instr_k<<<40, 256, 0, stream>>>(ws + o_hidden, ws + o_tagged, lengths, ws + o_instr);

    // ---- hoisted data-parallel phase ----
    prop_softmax_all_k<<<40, 256, 0, stream>>>(ws + o_instr, prop_emb, ws + o_psim5, ws + o_rsim5);
    iscale4_k<<<(4*Bb*2400 + 255)/256, 256, 0, stream>>>(ws + o_instr, ws + o_psim5, ws + o_iscl4);
    for (int step = 0; step < 4; step++){
        if (bigws) {
            mfma_node_k<<<Nn/64, 256, 0, stream>>>(
                nab, btn, ws + o_iscl4 + (size_t)step * Bb * 2400, node_indices,
                ws + o_wn, ws + o_nsc4 + (size_t)step * Nn);
            mfma_edge_k<<<Ee/64, 256, 0, stream>>>(
                eab, bte, ws + o_instr + step * 300, edge_batch,
                ws + o_wr, ws + o_es4 + (size_t)step * Ee);
        } else {
            mfma_node_f_k<<<Nn/64, 256, 0, stream>>>(
                node_attrs, btn, ws + o_iscl4 + (size_t)step * Bb * 2400, node_indices,
                ws + o_wn, ws + o_nsc4 + (size_t)step * Nn);
            mfma_edge_f_k<<<Ee/64, 256, 0, stream>>>(
                edge_attrs, bte, ws + o_instr + step * 300, edge_batch,
                ws + o_wr, ws + o_es4 + (size_t)step * Ee);
        }
    }

    // ---- fused serial message-passing tail ----
    msg_tail_k<<<Bb, 512, 0, stream>>>(edge_indices, edge_batch,
                                       ws + o_es4, ws + o_nsc4, ws + o_rsim5, ws + o_dist);

    // ---- final aggregation + FCs ----
    hipMemsetAsync(ws + o_agg, 0, 9600 * sizeof(float), stream);
    if (bigws)
        final_agg_bf_k<<<dim3(16,32), 320, 0, stream>>>(ws + o_psim5, ws + o_dist, nab, ws + o_agg);
    else
        final_agg_k<<<dim3(16,32), 320, 0, stream>>>(ws + o_psim5, ws + o_dist, node_attrs, ws + o_agg);
    fc1_k<<<75, 256, 0, stream>>>(ws + o_enc, ws + o_agg, fc1_W, fc1_b, ws + o_z);
    fc2_k<<<(Bb*1845 + 255)/256, 256, 0, stream>>>(ws + o_z, fc2_W, fc2_b, outf);
}

// Round 11
// 1581.381 us; speedup vs baseline: 2.3063x; 2.3063x over previous
//
#include <hip/hip_runtime.h>
#include <hip/hip_bf16.h>
#include <math.h>

#define Bb   32
#define Ll   30
#define Hh   300
#define Pp   8
#define Nn   16384
#define Ee   131072
#define NPG  512
#define NI   5

typedef __attribute__((ext_vector_type(4))) float f32x4;
typedef __attribute__((ext_vector_type(8))) short s16x8;

__device__ __forceinline__ float eluf(float x){ return x > 0.f ? x : expm1f(x); }
__device__ __forceinline__ float sigf(float x){ return 1.f/(1.f+expf(-x)); }
__device__ __forceinline__ float wave_sum(float s){
    s += __shfl_xor(s, 32); s += __shfl_xor(s, 16); s += __shfl_xor(s, 8);
    s += __shfl_xor(s, 4);  s += __shfl_xor(s, 2);  s += __shfl_xor(s, 1);
    return s;
}
__device__ __forceinline__ unsigned short f2bf(float x){
    unsigned u = __float_as_uint(x);
    unsigned r = u + 0x7FFFu + ((u >> 16) & 1u);
    return (unsigned short)(r >> 16);
}
__device__ __forceinline__ float bf2f(unsigned short v){
    return __uint_as_float(((unsigned)v) << 16);
}

// ---------------------------------------------------------------------------
// A-tile fetch
// ---------------------------------------------------------------------------
template<int KK, bool BFA>
__device__ __forceinline__ void fetch_as(const float* __restrict__ arowf,
                                         const unsigned short* __restrict__ arowb,
                                         const float* __restrict__ srow,
                                         int k, float* a8, float* s8)
{
    if constexpr (BFA) {
        s16x8 av = *(const s16x8*)(arowb + k);
        float4 w0 = *(const float4*)(srow + k), w1 = *(const float4*)(srow + k + 4);
        s8[0]=w0.x; s8[1]=w0.y; s8[2]=w0.z; s8[3]=w0.w; s8[4]=w1.x; s8[5]=w1.y; s8[6]=w1.z; s8[7]=w1.w;
        #pragma unroll
        for (int j = 0; j < 8; j++) a8[j] = bf2f((unsigned short)av[j]);
    } else {
        if (k + 8 <= KK) {
            float4 v0 = *(const float4*)(arowf + k), v1 = *(const float4*)(arowf + k + 4);
            a8[0]=v0.x; a8[1]=v0.y; a8[2]=v0.z; a8[3]=v0.w; a8[4]=v1.x; a8[5]=v1.y; a8[6]=v1.z; a8[7]=v1.w;
            float4 w0 = *(const float4*)(srow + k), w1 = *(const float4*)(srow + k + 4);
            s8[0]=w0.x; s8[1]=w0.y; s8[2]=w0.z; s8[3]=w0.w; s8[4]=w1.x; s8[5]=w1.y; s8[6]=w1.z; s8[7]=w1.w;
        } else {
            #pragma unroll
            for (int j = 0; j < 8; j++){ int kk = k + j; a8[j] = (kk < KK) ? arowf[kk] : 0.f; s8[j] = (kk < KK) ? srow[kk] : 0.f; }
        }
    }
}

// ---------------------------------------------------------------------------
// MFMA scored-GEMM (4 waves = 4 col quarters, 64 rows each)
// ---------------------------------------------------------------------------
template<int KK, int BPITCH, int NTILES, bool BFA>
__device__ __forceinline__ void mfma_score_impl(
    const float* __restrict__ Af, const unsigned short* __restrict__ Ab, int lda,
    const unsigned short* __restrict__ Bt,
    const float* __restrict__ S, int sstride, const int* __restrict__ rowb,
    const float* __restrict__ wpad,
    float* __restrict__ out)
{
    __shared__ unsigned short As[2][64*40];
    __shared__ unsigned short Bs[2][304*40];
    __shared__ float red[4][64];

    const int t = threadIdx.x;
    const int wc = t >> 6, lane = t & 63;
    const int l15 = lane & 15, g = lane >> 4;
    const int rowBlock = blockIdx.x * 64;

    const int sr = t >> 2;
    const int sk = (t & 3) * 8;
    const int grow = rowBlock + sr;
    const int bb = rowb[grow];
    const float* arowf = nullptr;
    const unsigned short* arowb = nullptr;
    if constexpr (BFA) arowb = Ab + (size_t)grow * lda;
    else               arowf = Af + (size_t)grow * lda;
    const float* srow = S + (size_t)bb * sstride;

    f32x4 acc[4][5];
    #pragma unroll
    for (int rt = 0; rt < 4; rt++)
        #pragma unroll
        for (int ct = 0; ct < 5; ct++) acc[rt][ct] = (f32x4){0.f,0.f,0.f,0.f};

    float a8[8], s8[8];
    s16x8 bvec[5];

    {
        fetch_as<KK, BFA>(arowf, arowb, srow, sk, a8, s8);
        #pragma unroll
        for (int i = 0; i < 5; i++){
            int v = t + 256 * i;
            if (v < 1216) bvec[i] = *(const s16x8*)&Bt[(size_t)(v >> 2) * BPITCH + ((v & 3) * 8)];
        }
        s16x8 pv;
        #pragma unroll
        for (int j = 0; j < 8; j++) pv[j] = (short)f2bf(a8[j] * s8[j]);
        *(s16x8*)&As[0][sr * 40 + sk] = pv;
        #pragma unroll
        for (int i = 0; i < 5; i++){
            int v = t + 256 * i;
            if (v < 1216) *(s16x8*)&Bs[0][(v >> 2) * 40 + ((v & 3) * 8)] = bvec[i];
        }
    }
    __syncthreads();

    int cur = 0;
    for (int kt = 0; kt < NTILES; ++kt) {
        if (kt + 1 < NTILES) {
            fetch_as<KK, BFA>(arowf, arowb, srow, (kt + 1) * 32 + sk, a8, s8);
            int k0 = (kt + 1) * 32;
            #pragma unroll
            for (int i = 0; i < 5; i++){
                int v = t + 256 * i;
                if (v < 1216) bvec[i] = *(const s16x8*)&Bt[(size_t)(v >> 2) * BPITCH + k0 + ((v & 3) * 8)];
            }
        }
        s16x8 af[4];
        #pragma unroll
        for (int rt = 0; rt < 4; rt++)
            af[rt] = *(s16x8*)&As[cur][(rt * 16 + l15) * 40 + g * 8];
        #pragma unroll
        for (int ct = 0; ct < 5; ct++) {
            if (wc == 3 && ct == 4) continue;
            int col = wc * 80 + ct * 16 + l15;
            s16x8 bf = *(s16x8*)&Bs[cur][col * 40 + g * 8];
            #pragma unroll
            for (int rt = 0; rt < 4; rt++)
                acc[rt][ct] = __builtin_amdgcn_mfma_f32_16x16x32_bf16(af[rt], bf, acc[rt][ct], 0, 0, 0);
        }
        if (kt + 1 < NTILES) {
            s16x8 pv;
            #pragma unroll
            for (int j = 0; j < 8; j++) pv[j] = (short)f2bf(a8[j] * s8[j]);
            *(s16x8*)&As[cur ^ 1][sr * 40 + sk] = pv;
            #pragma unroll
            for (int i = 0; i < 5; i++){
                int v = t + 256 * i;
                if (v < 1216) *(s16x8*)&Bs[cur ^ 1][(v >> 2) * 40 + ((v & 3) * 8)] = bvec[i];
            }
        }
        __syncthreads();
        cur ^= 1;
    }

    float p[4][4];
    #pragma unroll
    for (int rt = 0; rt < 4; rt++)
        #pragma unroll
        for (int i = 0; i < 4; i++) p[rt][i] = 0.f;
    #pragma unroll
    for (int ct = 0; ct < 5; ct++) {
        if (wc == 3 && ct == 4) continue;
        int col = wc * 80 + ct * 16 + l15;
        float wv = wpad[col];
        #pragma unroll
        for (int rt = 0; rt < 4; rt++)
            #pragma unroll
            for (int i = 0; i < 4; i++)
                p[rt][i] += eluf(acc[rt][ct][i]) * wv;
    }
    #pragma unroll
    for (int m = 1; m <= 8; m <<= 1) {
        #pragma unroll
        for (int rt = 0; rt < 4; rt++)
            #pragma unroll
            for (int i = 0; i < 4; i++)
                p[rt][i] += __shfl_xor(p[rt][i], m);
    }
    if (l15 == 0) {
        #pragma unroll
        for (int rt = 0; rt < 4; rt++)
            #pragma unroll
            for (int i = 0; i < 4; i++)
                red[wc][rt * 16 + g * 4 + i] = p[rt][i];
    }
    __syncthreads();
    if (t < 64)
        out[rowBlock + t] = red[0][t] + red[1][t] + red[2][t] + red[3][t];
}

__global__ __launch_bounds__(256, 2) void mfma_node_k(
    const unsigned short* __restrict__ Ab, const unsigned short* __restrict__ Bt,
    const float* __restrict__ S, const int* __restrict__ rowb,
    const float* __restrict__ wpad, float* __restrict__ out)
{
    mfma_score_impl<2400, 2400, 75, true>(nullptr, Ab, 2400, Bt, S, 2400, rowb, wpad, out);
}
__global__ __launch_bounds__(256, 2) void mfma_edge_k(
    const unsigned short* __restrict__ Ab, const unsigned short* __restrict__ Bt,
    const float* __restrict__ S, const int* __restrict__ rowb,
    const float* __restrict__ wpad, float* __restrict__ out)
{
    mfma_score_impl<320, 320, 10, true>(nullptr, Ab, 320, Bt, S, NI * 300, rowb, wpad, out);
}
__global__ __launch_bounds__(256, 2) void mfma_node_f_k(
    const float* __restrict__ A, const unsigned short* __restrict__ Bt,
    const float* __restrict__ S, const int* __restrict__ rowb,
    const float* __restrict__ wpad, float* __restrict__ out)
{
    mfma_score_impl<2400, 2400, 75, false>(A, nullptr, 2400, Bt, S, 2400, rowb, wpad, out);
}
__global__ __launch_bounds__(256, 2) void mfma_edge_f_k(
    const float* __restrict__ A, const unsigned short* __restrict__ Bt,
    const float* __restrict__ S, const int* __restrict__ rowb,
    const float* __restrict__ wpad, float* __restrict__ out)
{
    mfma_score_impl<300, 320, 10, false>(A, nullptr, 300, Bt, S, NI * 300, rowb, wpad, out);
}

// ---------------------------------------------------------------------------
// Generic MFMA GEMM. Optional fused add: C += simlast[row*2001] * qm[row*300+col]
// ---------------------------------------------------------------------------
__global__ __launch_bounds__(256, 2) void mfma_gemm_k(
    const float* __restrict__ A, int lda, int K, int ntiles,
    const unsigned short* __restrict__ Bt, int bpitch,
    int ncols, float* __restrict__ C, int ldc,
    const float* __restrict__ simlast, const float* __restrict__ qm)
{
    __shared__ unsigned short As[2][64*40];
    __shared__ unsigned short Bs[2][304*40];

    const int t = threadIdx.x;
    const int wc = t >> 6, lane = t & 63;
    const int l15 = lane & 15, g = lane >> 4;
    const int rowBlock = blockIdx.x * 64;
    const int colBlock = blockIdx.y * 304;

    const int sr = t >> 2, sk = (t & 3) * 8;
    const float* arow = A + (size_t)(rowBlock + sr) * lda;

    f32x4 acc[4][5];
    #pragma unroll
    for (int rt = 0; rt < 4; rt++)
        #pragma unroll
        for (int ct = 0; ct < 5; ct++) acc[rt][ct] = (f32x4){0.f,0.f,0.f,0.f};

    float a8[8];
    s16x8 bvec[5];

    {
        int k = sk;
        if (k + 8 <= K) {
            float4 v0 = *(const float4*)(arow + k), v1 = *(const float4*)(arow + k + 4);
            a8[0]=v0.x; a8[1]=v0.y; a8[2]=v0.z; a8[3]=v0.w; a8[4]=v1.x; a8[5]=v1.y; a8[6]=v1.z; a8[7]=v1.w;
        } else {
            #pragma unroll
            for (int j = 0; j < 8; j++){ int kk = k + j; a8[j] = (kk < K) ? arow[kk] : 0.f; }
        }
        #pragma unroll
        for (int i = 0; i < 5; i++){
            int v = t + 256 * i;
            if (v < 1216) bvec[i] = *(const s16x8*)&Bt[(size_t)(colBlock + (v >> 2)) * bpitch + ((v & 3) * 8)];
        }
        s16x8 pv;
        #pragma unroll
        for (int j = 0; j < 8; j++) pv[j] = (short)f2bf(a8[j]);
        *(s16x8*)&As[0][sr * 40 + sk] = pv;
        #pragma unroll
        for (int i = 0; i < 5; i++){
            int v = t + 256 * i;
            if (v < 1216) *(s16x8*)&Bs[0][(v >> 2) * 40 + ((v & 3) * 8)] = bvec[i];
        }
    }
    __syncthreads();

    int cur = 0;
    for (int kt = 0; kt < ntiles; ++kt) {
        if (kt + 1 < ntiles) {
            int k = (kt + 1) * 32 + sk;
            if (k + 8 <= K) {
                float4 v0 = *(const float4*)(arow + k), v1 = *(const float4*)(arow + k + 4);
                a8[0]=v0.x; a8[1]=v0.y; a8[2]=v0.z; a8[3]=v0.w; a8[4]=v1.x; a8[5]=v1.y; a8[6]=v1.z; a8[7]=v1.w;
            } else {
                #pragma unroll
                for (int j = 0; j < 8; j++){ int kk = k + j; a8[j] = (kk < K) ? arow[kk] : 0.f; }
            }
            int k0 = (kt + 1) * 32;
            #pragma unroll
            for (int i = 0; i < 5; i++){
                int v = t + 256 * i;
                if (v < 1216) bvec[i] = *(const s16x8*)&Bt[(size_t)(colBlock + (v >> 2)) * bpitch + k0 + ((v & 3) * 8)];
            }
        }
        s16x8 af[4];
        #pragma unroll
        for (int rt = 0; rt < 4; rt++)
            af[rt] = *(s16x8*)&As[cur][(rt * 16 + l15) * 40 + g * 8];
        #pragma unroll
        for (int ct = 0; ct < 5; ct++) {
            if (wc == 3 && ct == 4) continue;
            int col = wc * 80 + ct * 16 + l15;
            s16x8 bf = *(s16x8*)&Bs[cur][col * 40 + g * 8];
            #pragma unroll
            for (int rt = 0; rt < 4; rt++)
                acc[rt][ct] = __builtin_amdgcn_mfma_f32_16x16x32_bf16(af[rt], bf, acc[rt][ct], 0, 0, 0);
        }
        if (kt + 1 < ntiles) {
            s16x8 pv;
            #pragma unroll
            for (int j = 0; j < 8; j++) pv[j] = (short)f2bf(a8[j]);
            *(s16x8*)&As[cur ^ 1][sr * 40 + sk] = pv;
            #pragma unroll
            for (int i = 0; i < 5; i++){
                int v = t + 256 * i;
                if (v < 1216) *(s16x8*)&Bs[cur ^ 1][(v >> 2) * 40 + ((v & 3) * 8)] = bvec[i];
            }
        }
        __syncthreads();
        cur ^= 1;
    }

    #pragma unroll
    for (int ct = 0; ct < 5; ct++) {
        if (wc == 3 && ct == 4) continue;
        int col = colBlock + wc * 80 + ct * 16 + l15;
        if (col >= ncols) continue;
        #pragma unroll
        for (int rt = 0; rt < 4; rt++) {
            int row0 = rowBlock + rt * 16 + g * 4;
            #pragma unroll
            for (int i = 0; i < 4; i++) {
                float v = acc[rt][ct][i];
                int row = row0 + i;
                if (simlast) v += simlast[(size_t)row * 2001] * qm[(size_t)row * 300 + col];
                C[(size_t)row * ldc + col] = v;
            }
        }
    }
}

// ---------------------------------------------------------------------------
// Builders
// ---------------------------------------------------------------------------
__global__ void build_btg_k(const float* __restrict__ B, int K, int N,
                            int ncpad, int pitch, unsigned short* __restrict__ Bt)
{
    int idx = blockIdx.x * 256 + threadIdx.x;
    if (idx >= ncpad * pitch) return;
    int col = idx / pitch, k = idx - col * pitch;
    float v = (col < N && k < K) ? B[(size_t)k * N + col] : 0.f;
    Bt[idx] = f2bf(v);
}
__global__ void build_btr_k(const float* __restrict__ Bm, int R, int K,
                            int rpad, int pitch, unsigned short* __restrict__ Bt)
{
    int idx = blockIdx.x * 256 + threadIdx.x;
    if (idx >= rpad * pitch) return;
    int col = idx / pitch, k = idx - col * pitch;
    float v = (col < R && k < K) ? Bm[(size_t)col * K + k] : 0.f;
    Bt[idx] = f2bf(v);
}
__global__ void build_vocab_bt_k(const float* __restrict__ cv, const float* __restrict__ td,
                                 unsigned short* __restrict__ Bt)
{
    int idx = blockIdx.x * 256 + threadIdx.x;
    if (idx >= 2128 * 320) return;
    int col = idx / 320, k = idx - col * 320;
    float v = 0.f;
    if (k < 300) {
        if (col < 2000) v = cv[(size_t)col * 300 + k];
        else if (col == 2000) v = td[k];
    }
    Bt[idx] = f2bf(v);
}
// Pack lstm Whh [1200][300] -> bf16 k-major WT[k][1200]
__global__ void pack_whhT_k(const float* __restrict__ W, unsigned short* __restrict__ WT)
{
    int idx = blockIdx.x * 256 + threadIdx.x;
    if (idx >= 300 * 1200) return;
    int k = idx / 1200, r = idx - k * 1200;
    WT[idx] = f2bf(W[(size_t)r * 300 + k]);
}

__global__ void cvt_attr8_k(const float* __restrict__ src, long rows, int K, int pitch,
                            unsigned short* __restrict__ dst)
{
    const int pg = pitch >> 3;
    long total = rows * pg;
    for (long i = (long)blockIdx.x * blockDim.x + threadIdx.x; i < total;
         i += (long)gridDim.x * blockDim.x) {
        long r = i / pg;
        int kg = (int)(i - r * pg) * 8;
        s16x8 v;
        #pragma unroll
        for (int j = 0; j < 8; j++){
            int k = kg + j;
            float x = (k < K) ? src[r * (long)K + k] : 0.f;
            v[j] = (short)f2bf(x);
        }
        *(s16x8*)&dst[r * (long)pitch + kg] = v;
    }
}

__global__ void wpad_k(const float* __restrict__ wn, const float* __restrict__ wr,
                       float* __restrict__ wnp, float* __restrict__ wrp)
{
    int i = threadIdx.x;
    if (i < 304) { wnp[i] = (i < 300) ? wn[i] : 0.f; wrp[i] = (i < 300) ? wr[i] : 0.f; }
}

__global__ void transpose_k(const float* __restrict__ src, int R, int C,
                            float* __restrict__ dst)
{
    int idx = blockIdx.x * 256 + threadIdx.x;
    if (idx >= R * C) return;
    int r = idx / C, c = idx - r * C;
    dst[(size_t)c * R + r] = src[idx];
}

// ---------------------------------------------------------------------------
__global__ void softmax_rows_k(float* __restrict__ X, int nc)
{
    int row = blockIdx.x, t = threadIdx.x;
    __shared__ float red[256];
    size_t base = (size_t)row * nc;
    float m = -3.4e38f;
    for (int i = t; i < nc; i += 256) m = fmaxf(m, X[base + i]);
    red[t] = m; __syncthreads();
    for (int s = 128; s > 0; s >>= 1){ if (t < s) red[t] = fmaxf(red[t], red[t+s]); __syncthreads(); }
    float mx = red[0]; __syncthreads();
    float sm = 0.f;
    for (int i = t; i < nc; i += 256){ float e = expf(X[base + i] - mx); X[base + i] = e; sm += e; }
    red[t] = sm; __syncthreads();
    for (int s = 128; s > 0; s >>= 1){ if (t < s) red[t] += red[t+s]; __syncthreads(); }
    float inv = 1.f / red[0];
    for (int i = t; i < nc; i += 256) X[base + i] *= inv;
}

// Fast persistent LSTM (round-8 measured-good): seq access, 4 accumulators.
__global__ __launch_bounds__(640) void lstm_fast_k(
    const float* __restrict__ xW, const unsigned short* __restrict__ WT,
    const float* __restrict__ bih, const float* __restrict__ bhh,
    const int* __restrict__ lengths, float* __restrict__ encoded)
{
    __shared__ float hs[300];
    __shared__ float gs[1200];
    const int b = blockIdx.x, t = threadIdx.x;
    const int len = lengths[b];
    const bool ga = t < 600;
    const bool ha = t < 300;
    float bs0 = 0.f, bs1 = 0.f;
    if (ga) { bs0 = bih[2*t] + bhh[2*t]; bs1 = bih[2*t+1] + bhh[2*t+1]; }
    if (ha) hs[t] = 0.f;
    float c = 0.f, h = 0.f;
    __syncthreads();
    const float* xb = xW + (size_t)b * Ll * 1200;
    for (int st = 0; st < len; ++st) {
        if (ga) {
            float2 xv = *(const float2*)(xb + st * 1200 + 2 * t);
            float d0 = 0.f, d1 = 0.f, d2 = 0.f, d3 = 0.f;
            const unsigned short* wp = WT + 2 * t;
            #pragma unroll 8
            for (int k = 0; k < 300; k += 2) {
                float hk0 = hs[k], hk1 = hs[k + 1];
                unsigned wv0 = *(const unsigned*)(wp + (size_t)k * 1200);
                unsigned wv1 = *(const unsigned*)(wp + (size_t)(k + 1) * 1200);
                d0 = fmaf(hk0, __uint_as_float(wv0 << 16), d0);
                d1 = fmaf(hk0, __uint_as_float(wv0 & 0xFFFF0000u), d1);
                d2 = fmaf(hk1, __uint_as_float(wv1 << 16), d2);
                d3 = fmaf(hk1, __uint_as_float(wv1 & 0xFFFF0000u), d3);
            }
            gs[2*t]   = xv.x + bs0 + d0 + d2;
            gs[2*t+1] = xv.y + bs1 + d1 + d3;
        }
        __syncthreads();
        if (ha) {
            float i_ = sigf(gs[t]);
            float f_ = sigf(gs[300 + t]);
            float g_ = tanhf(gs[600 + t]);
            float o_ = sigf(gs[900 + t]);
            c = f_ * c + i_ * g_;
            h = o_ * tanhf(c);
            hs[t] = h;
        }
        __syncthreads();
    }
    if (ha) encoded[b * 300 + t] = h;
}

// Persistent RNN decoder
__global__ __launch_bounds__(320) void rnn_all_k(
    const float* __restrict__ enc, const float* __restrict__ WihT,
    const float* __restrict__ WhhT,
    const float* __restrict__ bih, const float* __restrict__ bhh,
    float* __restrict__ hidden)
{
    __shared__ float es[304];
    __shared__ float hs[304];
    const int b = blockIdx.x, i = threadIdx.x;
    const bool act = i < 300;
    if (act) { es[i] = enc[b * 300 + i]; hs[i] = 0.f; }
    __syncthreads();
    float ex = 0.f;
    if (act) {
        #pragma unroll 8
        for (int k = 0; k < 300; k++)
            ex = fmaf(es[k], WihT[(size_t)k * 300 + i], ex);
        ex += bih[i] + bhh[i];
    }
    for (int it = 0; it < NI; it++) {
        __syncthreads();
        float d = 0.f;
        if (act) {
            #pragma unroll 8
            for (int k = 0; k < 300; k++)
                d = fmaf(hs[k], WhhT[(size_t)k * 300 + i], d);
        }
        float v = fmaxf(ex + d, 0.f);
        __syncthreads();
        if (act) { hs[i] = v; hidden[((size_t)b * NI + it) * 300 + i] = v; }
    }
}

__global__ __launch_bounds__(256) void scores_instr_k(
    const float* __restrict__ hidden, const float* __restrict__ tagged,
    const int* __restrict__ lengths, float* __restrict__ instr)
{
    __shared__ float sc[4][32];
    int wv = threadIdx.x >> 6;
    int wid = blockIdx.x * 4 + wv;
    int lane = threadIdx.x & 63;
    int b = wid / NI;
    const float* hr = hidden + (size_t)wid * Hh;
    float hv[5];
    #pragma unroll
    for (int p = 0; p < 5; p++){ int k = lane + p * 64; hv[p] = (k < Hh) ? hr[k] : 0.f; }
    int len = lengths[b];
    for (int l = 0; l < Ll; l++){
        const float* trw = tagged + ((size_t)b * Ll + l) * Hh;
        float s = 0.f;
        #pragma unroll
        for (int p = 0; p < 5; p++){ int k = lane + p * 64; if (k < Hh) s += hv[p] * trw[k]; }
        s = wave_sum(s);
        if (lane == 0) sc[wv][l] = s;
    }
    __syncthreads();
    float mx = -3.4e38f;
    for (int l = 0; l < len; l++) mx = fmaxf(mx, sc[wv][l]);
    float sum = 0.f;
    for (int l = 0; l < len; l++) sum += expf(sc[wv][l] - mx);
    float inv = 1.f / sum;
    float a[5] = {0.f,0.f,0.f,0.f,0.f};
    for (int l = 0; l < len; l++){
        float pl = expf(sc[wv][l] - mx) * inv;
        const float* trw = tagged + ((size_t)b * Ll + l) * Hh;
        #pragma unroll
        for (int p = 0; p < 5; p++){ int k = lane + p * 64; if (k < Hh) a[p] += pl * trw[k]; }
    }
    #pragma unroll
    for (int p = 0; p < 5; p++){ int k = lane + p * 64; if (k < Hh) instr[(size_t)wid * Hh + k] = a[p]; }
}

__global__ __launch_bounds__(256) void prop_softmax_all_k(
    const float* __restrict__ instr, const float* __restrict__ pemb,
    float* __restrict__ psim5, float* __restrict__ rsim5)
{
    int wid = blockIdx.x * 4 + (threadIdx.x >> 6);
    int lane = threadIdx.x & 63;
    const float* ir = instr + (size_t)wid * Hh;
    float iv[5];
    #pragma unroll
    for (int p = 0; p < 5; p++){ int k = lane + p * 64; iv[p] = (k < Hh) ? ir[k] : 0.f; }
    float e[9];
    #pragma unroll
    for (int j = 0; j < 9; j++){
        const float* pr = pemb + j * Hh;
        float s = 0.f;
        #pragma unroll
        for (int p = 0; p < 5; p++){ int k = lane + p * 64; if (k < Hh) s += iv[p] * pr[k]; }
        e[j] = wave_sum(s);
    }
    if (lane == 0){
        float mx = e[0];
        #pragma unroll
        for (int j = 1; j < 9; j++) mx = fmaxf(mx, e[j]);
        float sum = 0.f;
        #pragma unroll
        for (int j = 0; j < 9; j++){ e[j] = expf(e[j] - mx); sum += e[j]; }
        float inv = 1.f / sum;
        #pragma unroll
        for (int p = 0; p < 8; p++) psim5[wid * 8 + p] = e[p] * inv;
        rsim5[wid] = e[8] * inv;
    }
}

__global__ void iscale4_k(const float* __restrict__ instr,
                          const float* __restrict__ psim5, float* __restrict__ iscale4)
{
    int idx = blockIdx.x * 256 + threadIdx.x;
    if (idx >= 4 * Bb * 2400) return;
    int step = idx / (Bb * 2400);
    int r = idx - step * (Bb * 2400);
    int b = r / 2400; int k = r - b * 2400;
    int p = k / 300;  int h = k - p * 300;
    iscale4[idx] = instr[((size_t)b * NI + step) * Hh + h] * psim5[(b * NI + step) * 8 + p];
}

__global__ void dist_init_const_k(float* __restrict__ dist)
{
    int n = blockIdx.x * 256 + threadIdx.x;
    if (n < Nn) dist[n] = 1.f / (float)NPG;   // node_indices[n] = n/512, 512 nodes/graph
}

__global__ void edge_msg_k(const int* __restrict__ ei, const float* __restrict__ es,
                           const float* __restrict__ dist, float* __restrict__ msgdot)
{
    int e = blockIdx.x * 256 + threadIdx.x;
    if (e < Ee){
        int s = ei[e];
        int d = ei[Ee + e];
        atomicAdd(&msgdot[d], dist[s] * es[e]);
    }
}

// seg_update also re-zeros its msgdot range for the next iteration.
__global__ __launch_bounds__(256) void seg_update_k(
    const float* __restrict__ nscore, float* __restrict__ msgdot,
    const float* __restrict__ rsim5, int step, float* __restrict__ dist)
{
    int b = blockIdx.x, t = threadIdx.x;
    __shared__ float red[256];
    int n0 = b * NPG;
    float a1 = nscore[n0 + t], a2 = nscore[n0 + 256 + t];
    float m1 = msgdot[n0 + t], m2 = msgdot[n0 + 256 + t];

    red[t] = fmaxf(a1, a2); __syncthreads();
    for (int s = 128; s > 0; s >>= 1){ if (t < s) red[t] = fmaxf(red[t], red[t+s]); __syncthreads(); }
    float mN = red[0]; __syncthreads();
    float e1 = expf(a1 - mN), e2 = expf(a2 - mN);
    red[t] = e1 + e2; __syncthreads();
    for (int s = 128; s > 0; s >>= 1){ if (t < s) red[t] += red[t+s]; __syncthreads(); }
    float sN = red[0]; __syncthreads();

    red[t] = fmaxf(m1, m2); __syncthreads();
    for (int s = 128; s > 0; s >>= 1){ if (t < s) red[t] = fmaxf(red[t], red[t+s]); __syncthreads(); }
    float mM = red[0]; __syncthreads();
    float f1 = expf(m1 - mM), f2 = expf(m2 - mM);
    red[t] = f1 + f2; __syncthreads();
    for (int s = 128; s > 0; s >>= 1){ if (t < s) red[t] += red[t+s]; __syncthreads(); }
    float sM = red[0];

    float rs = rsim5[b * NI + step];
    dist[n0 + t]       = rs * (f1 / sM) + (1.f - rs) * (e1 / sN);
    dist[n0 + 256 + t] = rs * (f2 / sM) + (1.f - rs) * (e2 / sN);
    msgdot[n0 + t] = 0.f;
    msgdot[n0 + 256 + t] = 0.f;
}

// final aggregation (bf16 attrs)
__global__ __launch_bounds__(320) void final_agg_bf_k(
    const float* __restrict__ psim5, const float* __restrict__ dist,
    const unsigned short* __restrict__ nab, float* __restrict__ agg)
{
    int chunk = blockIdx.x;
    int b = blockIdx.y;
    int h = threadIdx.x;
    if (h >= Hh) return;
    float ps[8];
    #pragma unroll
    for (int p = 0; p < 8; p++) ps[p] = psim5[(b * NI + 4) * 8 + p];
    float acc = 0.f;
    for (int i = 0; i < 32; i++){
        int n = b * NPG + chunk * 32 + i;
        const unsigned short* row = nab + (size_t)n * 2400;
        float wsum = 0.f;
        #pragma unroll
        for (int p = 0; p < 8; p++) wsum += ps[p] * bf2f(row[p * Hh + h]);
        acc += dist[n] * wsum;
    }
    atomicAdd(&agg[b * Hh + h], acc);
}
__global__ __launch_bounds__(320) void final_agg_k(
    const float* __restrict__ psim5, const float* __restrict__ dist,
    const float* __restrict__ na, float* __restrict__ agg)
{
    int chunk = blockIdx.x;
    int b = blockIdx.y;
    int h = threadIdx.x;
    if (h >= Hh) return;
    float ps[8];
    #pragma unroll
    for (int p = 0; p < 8; p++) ps[p] = psim5[(b * NI + 4) * 8 + p];
    float acc = 0.f;
    for (int i = 0; i < 32; i++){
        int n = b * NPG + chunk * 32 + i;
        const float* row = na + (size_t)n * Pp * Hh;
        float wsum = 0.f;
        #pragma unroll
        for (int p = 0; p < 8; p++) wsum += ps[p] * row[p * Hh + h];
        acc += dist[n] * wsum;
    }
    atomicAdd(&agg[b * Hh + h], acc);
}

// fc1 with fused feats (reads enc | agg directly), elu epilogue
__global__ void fc1_k(const float* __restrict__ enc, const float* __restrict__ agg,
                      const float* __restrict__ W, const float* __restrict__ bias,
                      float* __restrict__ z)
{
    int idx = blockIdx.x * 256 + threadIdx.x;
    if (idx >= Bb * 600) return;
    int m = idx / 600, j = idx - m * 600;
    const float* wr = W + (size_t)j * 600;
    float s = 0.f;
    for (int k = 0; k < 300; k++) s += enc[m * 300 + k] * wr[k];
    for (int k = 0; k < 300; k++) s += agg[m * 300 + k] * wr[300 + k];
    z[idx] = eluf(s + bias[j]);
}

__global__ void fc2_k(const float* __restrict__ z, const float* __restrict__ W,
                      const float* __restrict__ bias, float* __restrict__ out)
{
    int idx = blockIdx.x * 256 + threadIdx.x;
    if (idx >= Bb * 1845) return;
    int m = idx / 1845, j = idx - m * 1845;
    const float* wr = W + (size_t)j * 600;
    const float* zr = z + m * 600;
    float s = 0.f;
    for (int k = 0; k < 600; k++) s += zr[k] * wr[k];
    out[idx] = s + bias[j];
}

// ---------------------------------------------------------------------------
extern "C" void kernel_launch(void* const* d_in, const int* in_sizes, int n_in,
                              void* d_out, int out_size, void* d_ws, size_t ws_size,
                              hipStream_t stream)
{
    const float* questions      = (const float*)d_in[0];
    const int*   lengths        = (const int*)  d_in[1];
    const int*   node_indices   = (const int*)  d_in[2];
    const int*   edge_indices   = (const int*)  d_in[3];
    const int*   edge_batch     = (const int*)  d_in[4];
    const float* node_attrs     = (const float*)d_in[5];
    const float* edge_attrs     = (const float*)d_in[6];
    const float* concept_vocab  = (const float*)d_in[7];
    const float* prop_emb       = (const float*)d_in[8];
    const float* tagger_default = (const float*)d_in[9];
    const float* tagger_weight  = (const float*)d_in[10];
    const float* lstm_Wih       = (const float*)d_in[11];
    const float* lstm_Whh       = (const float*)d_in[12];
    const float* lstm_bih       = (const float*)d_in[13];
    const float* lstm_bhh       = (const float*)d_in[14];
    const float* rnn_Wih        = (const float*)d_in[15];
    const float* rnn_Whh        = (const float*)d_in[16];
    const float* rnn_bih        = (const float*)d_in[17];
    const float* rnn_bhh        = (const float*)d_in[18];
    const float* Wnp            = (const float*)d_in[19];
    const float* Wedge          = (const float*)d_in[20];
    const float* w_nscore       = (const float*)d_in[21];
    const float* w_rscore       = (const float*)d_in[22];
    const float* fc1_W          = (const float*)d_in[23];
    const float* fc1_b          = (const float*)d_in[24];
    const float* fc2_W          = (const float*)d_in[25];
    const float* fc2_b          = (const float*)d_in[26];
    float* outf = (float*)d_out;

    float* ws = (float*)d_ws;
    size_t off = 0;
    auto alloc = [&](size_t n){ size_t r = off; off += (n + 63) & ~(size_t)63; return r; };
    size_t o_q2     = alloc(960 * 300);
    size_t o_sim    = alloc((size_t)960 * 2001);
    size_t o_tagged = alloc(960 * 300);
    size_t o_xw     = alloc((size_t)960 * 1200);
    size_t o_enc    = alloc(9600);
    size_t o_hidden = alloc(48000);
    size_t o_instr  = alloc(48000);
    size_t o_psim5  = alloc(1280);
    size_t o_rsim5  = alloc(160);
    size_t o_iscl4  = alloc((size_t)4 * Bb * 2400);
    size_t o_nsc4   = alloc((size_t)4 * Nn);
    size_t o_es4    = alloc((size_t)4 * Ee);
    size_t o_msgdot = alloc(Nn);
    size_t o_dist   = alloc(Nn);
    size_t o_agg    = alloc(9600);
    size_t o_z      = alloc(19200);
    size_t o_btn    = alloc((size_t)304 * 2400 / 2);
    size_t o_bte    = alloc((size_t)304 * 320 / 2);
    size_t o_wn     = alloc(304);
    size_t o_wr     = alloc(304);
    size_t o_wlstm  = alloc(180000);                   // lstm Whh bf16 [300][1200]
    size_t o_rwhhT  = alloc(90000);
    size_t o_rwihT  = alloc(90000);
    size_t o_btq    = alloc((size_t)304 * 320 / 2);
    size_t o_btv    = alloc((size_t)2128 * 320 / 2);
    size_t o_btc    = alloc((size_t)304 * 2016 / 2);
    size_t o_btw    = alloc((size_t)1216 * 320 / 2);   // lstm_Wih as B^T
    size_t o_nab    = alloc((size_t)Nn * 2400 / 2);
    size_t o_eab    = alloc((size_t)Ee * 320 / 2);
    const bool bigws = ws_size >= off * sizeof(float);

    unsigned short* btn = (unsigned short*)(ws + o_btn);
    unsigned short* bte = (unsigned short*)(ws + o_bte);
    unsigned short* wlstm = (unsigned short*)(ws + o_wlstm);
    unsigned short* btq = (unsigned short*)(ws + o_btq);
    unsigned short* btv = (unsigned short*)(ws + o_btv);
    unsigned short* btc = (unsigned short*)(ws + o_btc);
    unsigned short* btw = (unsigned short*)(ws + o_btw);
    unsigned short* nab = (unsigned short*)(ws + o_nab);
    unsigned short* eab = (unsigned short*)(ws + o_eab);

    // ---- one-time conversions ----
    build_btg_k<<<(304*2400 + 255)/256, 256, 0, stream>>>(Wnp, 2400, 300, 304, 2400, btn);
    build_btg_k<<<(304*320 + 255)/256, 256, 0, stream>>>(Wedge, 300, 300, 304, 320, bte);
    wpad_k<<<1, 320, 0, stream>>>(w_nscore, w_rscore, ws + o_wn, ws + o_wr);
    pack_whhT_k<<<(300*1200 + 255)/256, 256, 0, stream>>>(lstm_Whh, wlstm);
    transpose_k<<<(300*300 + 255)/256, 256, 0, stream>>>(rnn_Whh, 300, 300, ws + o_rwhhT);
    transpose_k<<<(300*300 + 255)/256, 256, 0, stream>>>(rnn_Wih, 300, 300, ws + o_rwihT);
    build_btg_k<<<(304*320 + 255)/256, 256, 0, stream>>>(tagger_weight, 300, 300, 304, 320, btq);
    build_vocab_bt_k<<<(2128*320 + 255)/256, 256, 0, stream>>>(concept_vocab, tagger_default, btv);
    build_btg_k<<<(304*2016 + 255)/256, 256, 0, stream>>>(concept_vocab, 2000, 300, 304, 2016, btc);
    build_btr_k<<<(1216*320 + 255)/256, 256, 0, stream>>>(lstm_Wih, 1200, 300, 1216, 320, btw);
    if (bigws) {
        cvt_attr8_k<<<2048, 256, 0, stream>>>(node_attrs, Nn, 2400, 2400, nab);
        cvt_attr8_k<<<2048, 256, 0, stream>>>(edge_attrs, Ee, 300, 320, eab);
    }

    // ---- tagger chain ----
    mfma_gemm_k<<<dim3(15,1), 256, 0, stream>>>(
        questions, 300, 300, 10, btq, 320, 300, ws + o_q2, 300, nullptr, nullptr);
    mfma_gemm_k<<<dim3(15,7), 256, 0, stream>>>(
        ws + o_q2, 300, 300, 10, btv, 320, 2001, ws + o_sim, 2001, nullptr, nullptr);
    softmax_rows_k<<<960, 256, 0, stream>>>(ws + o_sim, 2001);
    // tagged = sim[:, :2000] @ concept_vocab  (+ fused sim[:,2000]*questions)
    mfma_gemm_k<<<dim3(15,1), 256, 0, stream>>>(
        ws + o_sim, 2001, 2000, 63, btc, 2016, 300, ws + o_tagged, 300,
        ws + o_sim + 2000, questions);

    // ---- LSTM ----
    mfma_gemm_k<<<dim3(15,4), 256, 0, stream>>>(
        ws + o_tagged, 300, 300, 10, btw, 320, 1200, ws + o_xw, 1200, nullptr, nullptr);
    lstm_fast_k<<<Bb, 640, 0, stream>>>(ws + o_xw, wlstm, lstm_bih, lstm_bhh,
                                        lengths, ws + o_enc);

    // ---- RNN + instructions ----
    rnn_all_k<<<Bb, 320, 0, stream>>>(ws + o_enc, ws + o_rwihT, ws + o_rwhhT,
                                      rnn_bih, rnn_bhh, ws + o_hidden);
    scores_instr_k<<<40, 256, 0, stream>>>(ws + o_hidden, ws + o_tagged, lengths, ws + o_instr);

    // ---- hoisted data-parallel phase ----
    prop_softmax_all_k<<<40, 256, 0, stream>>>(ws + o_instr, prop_emb, ws + o_psim5, ws + o_rsim5);
    iscale4_k<<<(4*Bb*2400 + 255)/256, 256, 0, stream>>>(ws + o_instr, ws + o_psim5, ws + o_iscl4);
    for (int step = 0; step < 4; step++){
        if (bigws) {
            mfma_node_k<<<Nn/64, 256, 0, stream>>>(
                nab, btn, ws + o_iscl4 + (size_t)step * Bb * 2400, node_indices,
                ws + o_wn, ws + o_nsc4 + (size_t)step * Nn);
            mfma_edge_k<<<Ee/64, 256, 0, stream>>>(
                eab, bte, ws + o_instr + step * 300, edge_batch,
                ws + o_wr, ws + o_es4 + (size_t)step * Ee);
        } else {
            mfma_node_f_k<<<Nn/64, 256, 0, stream>>>(
                node_attrs, btn, ws + o_iscl4 + (size_t)step * Bb * 2400, node_indices,
                ws + o_wn, ws + o_nsc4 + (size_t)step * Nn);
            mfma_edge_f_k<<<Ee/64, 256, 0, stream>>>(
                edge_attrs, bte, ws + o_instr + step * 300, edge_batch,
                ws + o_wr, ws + o_es4 + (size_t)step * Ee);
        }
    }

    // ---- serial message-passing tail (round-9 measured-good form) ----
    dist_init_const_k<<<64, 256, 0, stream>>>(ws + o_dist);
    hipMemsetAsync(ws + o_msgdot, 0, Nn * sizeof(float), stream);
    for (int step = 0; step < 4; step++){
        edge_msg_k<<<512, 256, 0, stream>>>(edge_indices, ws + o_es4 + (size_t)step * Ee,
                                            ws + o_dist, ws + o_msgdot);
        seg_update_k<<<32, 256, 0, stream>>>(ws + o_nsc4 + (size_t)step * Nn, ws + o_msgdot,
                                             ws + o_rsim5, step, ws + o_dist);
    }

    // ---- final aggregation + FCs ----
    hipMemsetAsync(ws + o_agg, 0, 9600 * sizeof(float), stream);
    if (bigws)
        final_agg_bf_k<<<dim3(16,32), 320, 0, stream>>>(ws + o_psim5, ws + o_dist, nab, ws + o_agg);
    else
        final_agg_k<<<dim3(16,32), 320, 0, stream>>>(ws + o_psim5, ws + o_dist, node_attrs, ws + o_agg);
    fc1_k<<<75, 256, 0, stream>>>(ws + o_enc, ws + o_agg, fc1_W, fc1_b, ws + o_z);
    fc2_k<<<(Bb*1845 + 255)/256, 256, 0, stream>>>(ws + o_z, fc2_W, fc2_b, outf);
}

// Round 12
// 1329.274 us; speedup vs baseline: 2.7437x; 1.1897x over previous
//
#include <hip/hip_runtime.h>
#include <hip/hip_bf16.h>
#include <math.h>

#define Bb   32
#define Ll   30
#define Hh   300
#define Pp   8
#define Nn   16384
#define Ee   131072
#define NPG  512
#define NI   5

typedef __attribute__((ext_vector_type(4))) float f32x4;
typedef __attribute__((ext_vector_type(8))) short s16x8;

__device__ __forceinline__ float eluf(float x){ return x > 0.f ? x : expm1f(x); }
__device__ __forceinline__ float sigf(float x){ return 1.f/(1.f+expf(-x)); }
__device__ __forceinline__ float wave_sum(float s){
    s += __shfl_xor(s, 32); s += __shfl_xor(s, 16); s += __shfl_xor(s, 8);
    s += __shfl_xor(s, 4);  s += __shfl_xor(s, 2);  s += __shfl_xor(s, 1);
    return s;
}
__device__ __forceinline__ unsigned short f2bf(float x){
    unsigned u = __float_as_uint(x);
    unsigned r = u + 0x7FFFu + ((u >> 16) & 1u);
    return (unsigned short)(r >> 16);
}
__device__ __forceinline__ float bf2f(unsigned short v){
    return __uint_as_float(((unsigned)v) << 16);
}

// ---------------------------------------------------------------------------
// A-tile fetch
// ---------------------------------------------------------------------------
template<int KK, bool BFA>
__device__ __forceinline__ void fetch_as(const float* __restrict__ arowf,
                                         const unsigned short* __restrict__ arowb,
                                         const float* __restrict__ srow,
                                         int k, float* a8, float* s8)
{
    if constexpr (BFA) {
        s16x8 av = *(const s16x8*)(arowb + k);
        float4 w0 = *(const float4*)(srow + k), w1 = *(const float4*)(srow + k + 4);
        s8[0]=w0.x; s8[1]=w0.y; s8[2]=w0.z; s8[3]=w0.w; s8[4]=w1.x; s8[5]=w1.y; s8[6]=w1.z; s8[7]=w1.w;
        #pragma unroll
        for (int j = 0; j < 8; j++) a8[j] = bf2f((unsigned short)av[j]);
    } else {
        if (k + 8 <= KK) {
            float4 v0 = *(const float4*)(arowf + k), v1 = *(const float4*)(arowf + k + 4);
            a8[0]=v0.x; a8[1]=v0.y; a8[2]=v0.z; a8[3]=v0.w; a8[4]=v1.x; a8[5]=v1.y; a8[6]=v1.z; a8[7]=v1.w;
            float4 w0 = *(const float4*)(srow + k), w1 = *(const float4*)(srow + k + 4);
            s8[0]=w0.x; s8[1]=w0.y; s8[2]=w0.z; s8[3]=w0.w; s8[4]=w1.x; s8[5]=w1.y; s8[6]=w1.z; s8[7]=w1.w;
        } else {
            #pragma unroll
            for (int j = 0; j < 8; j++){ int kk = k + j; a8[j] = (kk < KK) ? arowf[kk] : 0.f; s8[j] = (kk < KK) ? srow[kk] : 0.f; }
        }
    }
}

// ---------------------------------------------------------------------------
// MFMA scored-GEMM (4 waves = 4 col quarters, 64 rows each)
// ---------------------------------------------------------------------------
template<int KK, int BPITCH, int NTILES, bool BFA>
__device__ __forceinline__ void mfma_score_impl(
    const float* __restrict__ Af, const unsigned short* __restrict__ Ab, int lda,
    const unsigned short* __restrict__ Bt,
    const float* __restrict__ S, int sstride, const int* __restrict__ rowb,
    const float* __restrict__ wpad,
    float* __restrict__ out)
{
    __shared__ unsigned short As[2][64*40];
    __shared__ unsigned short Bs[2][304*40];
    __shared__ float red[4][64];

    const int t = threadIdx.x;
    const int wc = t >> 6, lane = t & 63;
    const int l15 = lane & 15, g = lane >> 4;
    const int rowBlock = blockIdx.x * 64;

    const int sr = t >> 2;
    const int sk = (t & 3) * 8;
    const int grow = rowBlock + sr;
    const int bb = rowb[grow];
    const float* arowf = nullptr;
    const unsigned short* arowb = nullptr;
    if constexpr (BFA) arowb = Ab + (size_t)grow * lda;
    else               arowf = Af + (size_t)grow * lda;
    const float* srow = S + (size_t)bb * sstride;

    f32x4 acc[4][5];
    #pragma unroll
    for (int rt = 0; rt < 4; rt++)
        #pragma unroll
        for (int ct = 0; ct < 5; ct++) acc[rt][ct] = (f32x4){0.f,0.f,0.f,0.f};

    float a8[8], s8[8];
    s16x8 bvec[5];

    {
        fetch_as<KK, BFA>(arowf, arowb, srow, sk, a8, s8);
        #pragma unroll
        for (int i = 0; i < 5; i++){
            int v = t + 256 * i;
            if (v < 1216) bvec[i] = *(const s16x8*)&Bt[(size_t)(v >> 2) * BPITCH + ((v & 3) * 8)];
        }
        s16x8 pv;
        #pragma unroll
        for (int j = 0; j < 8; j++) pv[j] = (short)f2bf(a8[j] * s8[j]);
        *(s16x8*)&As[0][sr * 40 + sk] = pv;
        #pragma unroll
        for (int i = 0; i < 5; i++){
            int v = t + 256 * i;
            if (v < 1216) *(s16x8*)&Bs[0][(v >> 2) * 40 + ((v & 3) * 8)] = bvec[i];
        }
    }
    __syncthreads();

    int cur = 0;
    for (int kt = 0; kt < NTILES; ++kt) {
        if (kt + 1 < NTILES) {
            fetch_as<KK, BFA>(arowf, arowb, srow, (kt + 1) * 32 + sk, a8, s8);
            int k0 = (kt + 1) * 32;
            #pragma unroll
            for (int i = 0; i < 5; i++){
                int v = t + 256 * i;
                if (v < 1216) bvec[i] = *(const s16x8*)&Bt[(size_t)(v >> 2) * BPITCH + k0 + ((v & 3) * 8)];
            }
        }
        s16x8 af[4];
        #pragma unroll
        for (int rt = 0; rt < 4; rt++)
            af[rt] = *(s16x8*)&As[cur][(rt * 16 + l15) * 40 + g * 8];
        #pragma unroll
        for (int ct = 0; ct < 5; ct++) {
            if (wc == 3 && ct == 4) continue;
            int col = wc * 80 + ct * 16 + l15;
            s16x8 bf = *(s16x8*)&Bs[cur][col * 40 + g * 8];
            #pragma unroll
            for (int rt = 0; rt < 4; rt++)
                acc[rt][ct] = __builtin_amdgcn_mfma_f32_16x16x32_bf16(af[rt], bf, acc[rt][ct], 0, 0, 0);
        }
        if (kt + 1 < NTILES) {
            s16x8 pv;
            #pragma unroll
            for (int j = 0; j < 8; j++) pv[j] = (short)f2bf(a8[j] * s8[j]);
            *(s16x8*)&As[cur ^ 1][sr * 40 + sk] = pv;
            #pragma unroll
            for (int i = 0; i < 5; i++){
                int v = t + 256 * i;
                if (v < 1216) *(s16x8*)&Bs[cur ^ 1][(v >> 2) * 40 + ((v & 3) * 8)] = bvec[i];
            }
        }
        __syncthreads();
        cur ^= 1;
    }

    float p[4][4];
    #pragma unroll
    for (int rt = 0; rt < 4; rt++)
        #pragma unroll
        for (int i = 0; i < 4; i++) p[rt][i] = 0.f;
    #pragma unroll
    for (int ct = 0; ct < 5; ct++) {
        if (wc == 3 && ct == 4) continue;
        int col = wc * 80 + ct * 16 + l15;
        float wv = wpad[col];
        #pragma unroll
        for (int rt = 0; rt < 4; rt++)
            #pragma unroll
            for (int i = 0; i < 4; i++)
                p[rt][i] += eluf(acc[rt][ct][i]) * wv;
    }
    #pragma unroll
    for (int m = 1; m <= 8; m <<= 1) {
        #pragma unroll
        for (int rt = 0; rt < 4; rt++)
            #pragma unroll
            for (int i = 0; i < 4; i++)
                p[rt][i] += __shfl_xor(p[rt][i], m);
    }
    if (l15 == 0) {
        #pragma unroll
        for (int rt = 0; rt < 4; rt++)
            #pragma unroll
            for (int i = 0; i < 4; i++)
                red[wc][rt * 16 + g * 4 + i] = p[rt][i];
    }
    __syncthreads();
    if (t < 64)
        out[rowBlock + t] = red[0][t] + red[1][t] + red[2][t] + red[3][t];
}

// Batched over steps: blockIdx.y = step (0..3)
__global__ __launch_bounds__(256, 2) void mfma_node_k(
    const unsigned short* __restrict__ Ab, const unsigned short* __restrict__ Bt,
    const float* __restrict__ iscl4, const int* __restrict__ rowb,
    const float* __restrict__ wpad, float* __restrict__ nsc4)
{
    const int step = blockIdx.y;
    mfma_score_impl<2400, 2400, 75, true>(nullptr, Ab, 2400, Bt,
        iscl4 + (size_t)step * Bb * 2400, 2400, rowb, wpad,
        nsc4 + (size_t)step * Nn);
}
__global__ __launch_bounds__(256, 2) void mfma_edge_k(
    const unsigned short* __restrict__ Ab, const unsigned short* __restrict__ Bt,
    const float* __restrict__ instr, const int* __restrict__ rowb,
    const float* __restrict__ wpad, float* __restrict__ es4)
{
    const int step = blockIdx.y;
    mfma_score_impl<320, 320, 10, true>(nullptr, Ab, 320, Bt,
        instr + step * 300, NI * 300, rowb, wpad,
        es4 + (size_t)step * Ee);
}
__global__ __launch_bounds__(256, 2) void mfma_node_f_k(
    const float* __restrict__ A, const unsigned short* __restrict__ Bt,
    const float* __restrict__ iscl4, const int* __restrict__ rowb,
    const float* __restrict__ wpad, float* __restrict__ nsc4)
{
    const int step = blockIdx.y;
    mfma_score_impl<2400, 2400, 75, false>(A, nullptr, 2400, Bt,
        iscl4 + (size_t)step * Bb * 2400, 2400, rowb, wpad,
        nsc4 + (size_t)step * Nn);
}
__global__ __launch_bounds__(256, 2) void mfma_edge_f_k(
    const float* __restrict__ A, const unsigned short* __restrict__ Bt,
    const float* __restrict__ instr, const int* __restrict__ rowb,
    const float* __restrict__ wpad, float* __restrict__ es4)
{
    const int step = blockIdx.y;
    mfma_score_impl<300, 320, 10, false>(A, nullptr, 300, Bt,
        instr + step * 300, NI * 300, rowb, wpad,
        es4 + (size_t)step * Ee);
}

// ---------------------------------------------------------------------------
// Generic MFMA GEMM. Optional fused add: C += simlast[row*2001] * qm[row*300+col]
// ---------------------------------------------------------------------------
__global__ __launch_bounds__(256, 2) void mfma_gemm_k(
    const float* __restrict__ A, int lda, int K, int ntiles,
    const unsigned short* __restrict__ Bt, int bpitch,
    int ncols, float* __restrict__ C, int ldc,
    const float* __restrict__ simlast, const float* __restrict__ qm)
{
    __shared__ unsigned short As[2][64*40];
    __shared__ unsigned short Bs[2][304*40];

    const int t = threadIdx.x;
    const int wc = t >> 6, lane = t & 63;
    const int l15 = lane & 15, g = lane >> 4;
    const int rowBlock = blockIdx.x * 64;
    const int colBlock = blockIdx.y * 304;

    const int sr = t >> 2, sk = (t & 3) * 8;
    const float* arow = A + (size_t)(rowBlock + sr) * lda;

    f32x4 acc[4][5];
    #pragma unroll
    for (int rt = 0; rt < 4; rt++)
        #pragma unroll
        for (int ct = 0; ct < 5; ct++) acc[rt][ct] = (f32x4){0.f,0.f,0.f,0.f};

    float a8[8];
    s16x8 bvec[5];

    {
        int k = sk;
        if (k + 8 <= K) {
            float4 v0 = *(const float4*)(arow + k), v1 = *(const float4*)(arow + k + 4);
            a8[0]=v0.x; a8[1]=v0.y; a8[2]=v0.z; a8[3]=v0.w; a8[4]=v1.x; a8[5]=v1.y; a8[6]=v1.z; a8[7]=v1.w;
        } else {
            #pragma unroll
            for (int j = 0; j < 8; j++){ int kk = k + j; a8[j] = (kk < K) ? arow[kk] : 0.f; }
        }
        #pragma unroll
        for (int i = 0; i < 5; i++){
            int v = t + 256 * i;
            if (v < 1216) bvec[i] = *(const s16x8*)&Bt[(size_t)(colBlock + (v >> 2)) * bpitch + ((v & 3) * 8)];
        }
        s16x8 pv;
        #pragma unroll
        for (int j = 0; j < 8; j++) pv[j] = (short)f2bf(a8[j]);
        *(s16x8*)&As[0][sr * 40 + sk] = pv;
        #pragma unroll
        for (int i = 0; i < 5; i++){
            int v = t + 256 * i;
            if (v < 1216) *(s16x8*)&Bs[0][(v >> 2) * 40 + ((v & 3) * 8)] = bvec[i];
        }
    }
    __syncthreads();

    int cur = 0;
    for (int kt = 0; kt < ntiles; ++kt) {
        if (kt + 1 < ntiles) {
            int k = (kt + 1) * 32 + sk;
            if (k + 8 <= K) {
                float4 v0 = *(const float4*)(arow + k), v1 = *(const float4*)(arow + k + 4);
                a8[0]=v0.x; a8[1]=v0.y; a8[2]=v0.z; a8[3]=v0.w; a8[4]=v1.x; a8[5]=v1.y; a8[6]=v1.z; a8[7]=v1.w;
            } else {
                #pragma unroll
                for (int j = 0; j < 8; j++){ int kk = k + j; a8[j] = (kk < K) ? arow[kk] : 0.f; }
            }
            int k0 = (kt + 1) * 32;
            #pragma unroll
            for (int i = 0; i < 5; i++){
                int v = t + 256 * i;
                if (v < 1216) bvec[i] = *(const s16x8*)&Bt[(size_t)(colBlock + (v >> 2)) * bpitch + k0 + ((v & 3) * 8)];
            }
        }
        s16x8 af[4];
        #pragma unroll
        for (int rt = 0; rt < 4; rt++)
            af[rt] = *(s16x8*)&As[cur][(rt * 16 + l15) * 40 + g * 8];
        #pragma unroll
        for (int ct = 0; ct < 5; ct++) {
            if (wc == 3 && ct == 4) continue;
            int col = wc * 80 + ct * 16 + l15;
            s16x8 bf = *(s16x8*)&Bs[cur][col * 40 + g * 8];
            #pragma unroll
            for (int rt = 0; rt < 4; rt++)
                acc[rt][ct] = __builtin_amdgcn_mfma_f32_16x16x32_bf16(af[rt], bf, acc[rt][ct], 0, 0, 0);
        }
        if (kt + 1 < ntiles) {
            s16x8 pv;
            #pragma unroll
            for (int j = 0; j < 8; j++) pv[j] = (short)f2bf(a8[j]);
            *(s16x8*)&As[cur ^ 1][sr * 40 + sk] = pv;
            #pragma unroll
            for (int i = 0; i < 5; i++){
                int v = t + 256 * i;
                if (v < 1216) *(s16x8*)&Bs[cur ^ 1][(v >> 2) * 40 + ((v & 3) * 8)] = bvec[i];
            }
        }
        __syncthreads();
        cur ^= 1;
    }

    #pragma unroll
    for (int ct = 0; ct < 5; ct++) {
        if (wc == 3 && ct == 4) continue;
        int col = colBlock + wc * 80 + ct * 16 + l15;
        if (col >= ncols) continue;
        #pragma unroll
        for (int rt = 0; rt < 4; rt++) {
            int row0 = rowBlock + rt * 16 + g * 4;
            #pragma unroll
            for (int i = 0; i < 4; i++) {
                float v = acc[rt][ct][i];
                int row = row0 + i;
                if (simlast) v += simlast[(size_t)row * 2001] * qm[(size_t)row * 300 + col];
                C[(size_t)row * ldc + col] = v;
            }
        }
    }
}

// ---------------------------------------------------------------------------
// ONE prep kernel: all weight-table builds (flat-index range dispatch).
// ---------------------------------------------------------------------------
#define R_BTN   729600              // btn:  304x2400
#define R_BTE   (R_BTN + 97280)     // bte:  304x320
#define R_BTQ   (R_BTE + 97280)     // btq:  304x320
#define R_BTV   (R_BTQ + 680960)    // btv:  2128x320
#define R_BTC   (R_BTV + 612864)    // btc:  304x2016
#define R_BTW   (R_BTC + 389120)    // btw:  1216x320
#define R_WL    (R_BTW + 360000)    // wlstm: 300x1200
#define R_RWH   (R_WL + 90000)      // rwhhT
#define R_RWI   (R_RWH + 90000)     // rwihT
#define R_WP    (R_RWI + 608)       // wpad 2x304
#define R_TOTAL R_WP

__global__ void prep_all_k(
    const float* __restrict__ Wnp, const float* __restrict__ Wedge,
    const float* __restrict__ tagger_weight, const float* __restrict__ cv,
    const float* __restrict__ td, const float* __restrict__ lstm_Wih,
    const float* __restrict__ lstm_Whh, const float* __restrict__ rnn_Whh,
    const float* __restrict__ rnn_Wih, const float* __restrict__ wn,
    const float* __restrict__ wr,
    unsigned short* __restrict__ btn, unsigned short* __restrict__ bte,
    unsigned short* __restrict__ btq, unsigned short* __restrict__ btv,
    unsigned short* __restrict__ btc, unsigned short* __restrict__ btw,
    unsigned short* __restrict__ wlstm, float* __restrict__ rwhhT,
    float* __restrict__ rwihT, float* __restrict__ wnp, float* __restrict__ wrp)
{
    int idx = blockIdx.x * 256 + threadIdx.x;
    if (idx >= R_TOTAL) return;
    if (idx < R_BTN) {
        int col = idx / 2400, k = idx - col * 2400;
        btn[idx] = f2bf((col < 300) ? Wnp[(size_t)k * 300 + col] : 0.f);
    } else if (idx < R_BTE) {
        int r = idx - R_BTN;
        int col = r / 320, k = r - col * 320;
        bte[r] = f2bf((col < 300 && k < 300) ? Wedge[(size_t)k * 300 + col] : 0.f);
    } else if (idx < R_BTQ) {
        int r = idx - R_BTE;
        int col = r / 320, k = r - col * 320;
        btq[r] = f2bf((col < 300 && k < 300) ? tagger_weight[(size_t)k * 300 + col] : 0.f);
    } else if (idx < R_BTV) {
        int r = idx - R_BTQ;
        int col = r / 320, k = r - col * 320;
        float v = 0.f;
        if (k < 300) {
            if (col < 2000) v = cv[(size_t)col * 300 + k];
            else if (col == 2000) v = td[k];
        }
        btv[r] = f2bf(v);
    } else if (idx < R_BTC) {
        int r = idx - R_BTV;
        int col = r / 2016, k = r - col * 2016;
        btc[r] = f2bf((col < 300 && k < 2000) ? cv[(size_t)k * 300 + col] : 0.f);
    } else if (idx < R_BTW) {
        int r = idx - R_BTC;
        int col = r / 320, k = r - col * 320;
        btw[r] = f2bf((col < 1200 && k < 300) ? lstm_Wih[(size_t)col * 300 + k] : 0.f);
    } else if (idx < R_WL) {
        int r = idx - R_BTW;
        int k = r / 1200, row = r - k * 1200;
        wlstm[r] = f2bf(lstm_Whh[(size_t)row * 300 + k]);
    } else if (idx < R_RWH) {
        int r = idx - R_WL;
        int row = r / 300, c = r - row * 300;
        rwhhT[(size_t)c * 300 + row] = rnn_Whh[r];
    } else if (idx < R_RWI) {
        int r = idx - R_RWH;
        int row = r / 300, c = r - row * 300;
        rwihT[(size_t)c * 300 + row] = rnn_Wih[r];
    } else {
        int r = idx - R_RWI;
        if (r < 304) wnp[r] = (r < 300) ? wn[r] : 0.f;
        else { int r2 = r - 304; wrp[r2] = (r2 < 300) ? wr[r2] : 0.f; }
    }
}

// ONE convert kernel for both attr arrays (grid-stride over vec8 groups)
__global__ void cvt_both_k(const float* __restrict__ na, const float* __restrict__ ea,
                           unsigned short* __restrict__ nab, unsigned short* __restrict__ eab)
{
    const long NG = (long)Nn * 300;            // node vec8 groups (2400/8)
    const long EG = (long)Ee * 40;             // edge vec8 groups (320/8)
    const long total = NG + EG;
    for (long i = (long)blockIdx.x * blockDim.x + threadIdx.x; i < total;
         i += (long)gridDim.x * blockDim.x) {
        if (i < NG) {
            long base = i * 8;                 // dense: pitch == K == 2400
            float4 v0 = *(const float4*)(na + base);
            float4 v1 = *(const float4*)(na + base + 4);
            s16x8 v;
            v[0]=(short)f2bf(v0.x); v[1]=(short)f2bf(v0.y); v[2]=(short)f2bf(v0.z); v[3]=(short)f2bf(v0.w);
            v[4]=(short)f2bf(v1.x); v[5]=(short)f2bf(v1.y); v[6]=(short)f2bf(v1.z); v[7]=(short)f2bf(v1.w);
            *(s16x8*)&nab[base] = v;
        } else {
            long r2 = i - NG;
            long row = r2 / 40;
            int kg = (int)(r2 - row * 40) * 8;
            s16x8 v;
            #pragma unroll
            for (int j = 0; j < 8; j++){
                int k = kg + j;
                float x = (k < 300) ? ea[row * 300 + k] : 0.f;
                v[j] = (short)f2bf(x);
            }
            *(s16x8*)&eab[row * 320 + kg] = v;
        }
    }
}

// dist = 1/512, msgdot = 0, agg = 0 (one launch)
__global__ void init_k(float* __restrict__ dist, float* __restrict__ msgdot,
                       float* __restrict__ agg)
{
    int n = blockIdx.x * 256 + threadIdx.x;
    if (n < Nn) { dist[n] = 1.f / (float)NPG; msgdot[n] = 0.f; }
    if (n < 9600) agg[n] = 0.f;
}

// ---------------------------------------------------------------------------
__global__ void softmax_rows_k(float* __restrict__ X, int nc)
{
    int row = blockIdx.x, t = threadIdx.x;
    __shared__ float red[256];
    size_t base = (size_t)row * nc;
    float m = -3.4e38f;
    for (int i = t; i < nc; i += 256) m = fmaxf(m, X[base + i]);
    red[t] = m; __syncthreads();
    for (int s = 128; s > 0; s >>= 1){ if (t < s) red[t] = fmaxf(red[t], red[t+s]); __syncthreads(); }
    float mx = red[0]; __syncthreads();
    float sm = 0.f;
    for (int i = t; i < nc; i += 256){ float e = expf(X[base + i] - mx); X[base + i] = e; sm += e; }
    red[t] = sm; __syncthreads();
    for (int s = 128; s > 0; s >>= 1){ if (t < s) red[t] += red[t+s]; __syncthreads(); }
    float inv = 1.f / red[0];
    for (int i = t; i < nc; i += 256) X[base + i] *= inv;
}

// Fast persistent LSTM (round-8 measured-good)
__global__ __launch_bounds__(640) void lstm_fast_k(
    const float* __restrict__ xW, const unsigned short* __restrict__ WT,
    const float* __restrict__ bih, const float* __restrict__ bhh,
    const int* __restrict__ lengths, float* __restrict__ encoded)
{
    __shared__ float hs[300];
    __shared__ float gs[1200];
    const int b = blockIdx.x, t = threadIdx.x;
    const int len = lengths[b];
    const bool ga = t < 600;
    const bool ha = t < 300;
    float bs0 = 0.f, bs1 = 0.f;
    if (ga) { bs0 = bih[2*t] + bhh[2*t]; bs1 = bih[2*t+1] + bhh[2*t+1]; }
    if (ha) hs[t] = 0.f;
    float c = 0.f, h = 0.f;
    __syncthreads();
    const float* xb = xW + (size_t)b * Ll * 1200;
    for (int st = 0; st < len; ++st) {
        if (ga) {
            float2 xv = *(const float2*)(xb + st * 1200 + 2 * t);
            float d0 = 0.f, d1 = 0.f, d2 = 0.f, d3 = 0.f;
            const unsigned short* wp = WT + 2 * t;
            #pragma unroll 8
            for (int k = 0; k < 300; k += 2) {
                float hk0 = hs[k], hk1 = hs[k + 1];
                unsigned wv0 = *(const unsigned*)(wp + (size_t)k * 1200);
                unsigned wv1 = *(const unsigned*)(wp + (size_t)(k + 1) * 1200);
                d0 = fmaf(hk0, __uint_as_float(wv0 << 16), d0);
                d1 = fmaf(hk0, __uint_as_float(wv0 & 0xFFFF0000u), d1);
                d2 = fmaf(hk1, __uint_as_float(wv1 << 16), d2);
                d3 = fmaf(hk1, __uint_as_float(wv1 & 0xFFFF0000u), d3);
            }
            gs[2*t]   = xv.x + bs0 + d0 + d2;
            gs[2*t+1] = xv.y + bs1 + d1 + d3;
        }
        __syncthreads();
        if (ha) {
            float i_ = sigf(gs[t]);
            float f_ = sigf(gs[300 + t]);
            float g_ = tanhf(gs[600 + t]);
            float o_ = sigf(gs[900 + t]);
            c = f_ * c + i_ * g_;
            h = o_ * tanhf(c);
            hs[t] = h;
        }
        __syncthreads();
    }
    if (ha) encoded[b * 300 + t] = h;
}

// Persistent RNN decoder
__global__ __launch_bounds__(320) void rnn_all_k(
    const float* __restrict__ enc, const float* __restrict__ WihT,
    const float* __restrict__ WhhT,
    const float* __restrict__ bih, const float* __restrict__ bhh,
    float* __restrict__ hidden)
{
    __shared__ float es[304];
    __shared__ float hs[304];
    const int b = blockIdx.x, i = threadIdx.x;
    const bool act = i < 300;
    if (act) { es[i] = enc[b * 300 + i]; hs[i] = 0.f; }
    __syncthreads();
    float ex = 0.f;
    if (act) {
        #pragma unroll 8
        for (int k = 0; k < 300; k++)
            ex = fmaf(es[k], WihT[(size_t)k * 300 + i], ex);
        ex += bih[i] + bhh[i];
    }
    for (int it = 0; it < NI; it++) {
        __syncthreads();
        float d = 0.f;
        if (act) {
            #pragma unroll 8
            for (int k = 0; k < 300; k++)
                d = fmaf(hs[k], WhhT[(size_t)k * 300 + i], d);
        }
        float v = fmaxf(ex + d, 0.f);
        __syncthreads();
        if (act) { hs[i] = v; hidden[((size_t)b * NI + it) * 300 + i] = v; }
    }
}

__global__ __launch_bounds__(256) void scores_instr_k(
    const float* __restrict__ hidden, const float* __restrict__ tagged,
    const int* __restrict__ lengths, float* __restrict__ instr)
{
    __shared__ float sc[4][32];
    int wv = threadIdx.x >> 6;
    int wid = blockIdx.x * 4 + wv;
    int lane = threadIdx.x & 63;
    int b = wid / NI;
    const float* hr = hidden + (size_t)wid * Hh;
    float hv[5];
    #pragma unroll
    for (int p = 0; p < 5; p++){ int k = lane + p * 64; hv[p] = (k < Hh) ? hr[k] : 0.f; }
    int len = lengths[b];
    for (int l = 0; l < Ll; l++){
        const float* trw = tagged + ((size_t)b * Ll + l) * Hh;
        float s = 0.f;
        #pragma unroll
        for (int p = 0; p < 5; p++){ int k = lane + p * 64; if (k < Hh) s += hv[p] * trw[k]; }
        s = wave_sum(s);
        if (lane == 0) sc[wv][l] = s;
    }
    __syncthreads();
    float mx = -3.4e38f;
    for (int l = 0; l < len; l++) mx = fmaxf(mx, sc[wv][l]);
    float sum = 0.f;
    for (int l = 0; l < len; l++) sum += expf(sc[wv][l] - mx);
    float inv = 1.f / sum;
    float a[5] = {0.f,0.f,0.f,0.f,0.f};
    for (int l = 0; l < len; l++){
        float pl = expf(sc[wv][l] - mx) * inv;
        const float* trw = tagged + ((size_t)b * Ll + l) * Hh;
        #pragma unroll
        for (int p = 0; p < 5; p++){ int k = lane + p * 64; if (k < Hh) a[p] += pl * trw[k]; }
    }
    #pragma unroll
    for (int p = 0; p < 5; p++){ int k = lane + p * 64; if (k < Hh) instr[(size_t)wid * Hh + k] = a[p]; }
}

__global__ __launch_bounds__(256) void prop_softmax_all_k(
    const float* __restrict__ instr, const float* __restrict__ pemb,
    float* __restrict__ psim5, float* __restrict__ rsim5)
{
    int wid = blockIdx.x * 4 + (threadIdx.x >> 6);
    int lane = threadIdx.x & 63;
    const float* ir = instr + (size_t)wid * Hh;
    float iv[5];
    #pragma unroll
    for (int p = 0; p < 5; p++){ int k = lane + p * 64; iv[p] = (k < Hh) ? ir[k] : 0.f; }
    float e[9];
    #pragma unroll
    for (int j = 0; j < 9; j++){
        const float* pr = pemb + j * Hh;
        float s = 0.f;
        #pragma unroll
        for (int p = 0; p < 5; p++){ int k = lane + p * 64; if (k < Hh) s += iv[p] * pr[k]; }
        e[j] = wave_sum(s);
    }
    if (lane == 0){
        float mx = e[0];
        #pragma unroll
        for (int j = 1; j < 9; j++) mx = fmaxf(mx, e[j]);
        float sum = 0.f;
        #pragma unroll
        for (int j = 0; j < 9; j++){ e[j] = expf(e[j] - mx); sum += e[j]; }
        float inv = 1.f / sum;
        #pragma unroll
        for (int p = 0; p < 8; p++) psim5[wid * 8 + p] = e[p] * inv;
        rsim5[wid] = e[8] * inv;
    }
}

__global__ void iscale4_k(const float* __restrict__ instr,
                          const float* __restrict__ psim5, float* __restrict__ iscale4)
{
    int idx = blockIdx.x * 256 + threadIdx.x;
    if (idx >= 4 * Bb * 2400) return;
    int step = idx / (Bb * 2400);
    int r = idx - step * (Bb * 2400);
    int b = r / 2400; int k = r - b * 2400;
    int p = k / 300;  int h = k - p * 300;
    iscale4[idx] = instr[((size_t)b * NI + step) * Hh + h] * psim5[(b * NI + step) * 8 + p];
}

__global__ void edge_msg_k(const int* __restrict__ ei, const float* __restrict__ es,
                           const float* __restrict__ dist, float* __restrict__ msgdot)
{
    int e = blockIdx.x * 256 + threadIdx.x;
    if (e < Ee){
        int s = ei[e];
        int d = ei[Ee + e];
        atomicAdd(&msgdot[d], dist[s] * es[e]);
    }
}

// seg_update also re-zeros its msgdot range for the next iteration.
__global__ __launch_bounds__(256) void seg_update_k(
    const float* __restrict__ nscore, float* __restrict__ msgdot,
    const float* __restrict__ rsim5, int step, float* __restrict__ dist)
{
    int b = blockIdx.x, t = threadIdx.x;
    __shared__ float red[256];
    int n0 = b * NPG;
    float a1 = nscore[n0 + t], a2 = nscore[n0 + 256 + t];
    float m1 = msgdot[n0 + t], m2 = msgdot[n0 + 256 + t];

    red[t] = fmaxf(a1, a2); __syncthreads();
    for (int s = 128; s > 0; s >>= 1){ if (t < s) red[t] = fmaxf(red[t], red[t+s]); __syncthreads(); }
    float mN = red[0]; __syncthreads();
    float e1 = expf(a1 - mN), e2 = expf(a2 - mN);
    red[t] = e1 + e2; __syncthreads();
    for (int s = 128; s > 0; s >>= 1){ if (t < s) red[t] += red[t+s]; __syncthreads(); }
    float sN = red[0]; __syncthreads();

    red[t] = fmaxf(m1, m2); __syncthreads();
    for (int s = 128; s > 0; s >>= 1){ if (t < s) red[t] = fmaxf(red[t], red[t+s]); __syncthreads(); }
    float mM = red[0]; __syncthreads();
    float f1 = expf(m1 - mM), f2 = expf(m2 - mM);
    red[t] = f1 + f2; __syncthreads();
    for (int s = 128; s > 0; s >>= 1){ if (t < s) red[t] += red[t+s]; __syncthreads(); }
    float sM = red[0];

    float rs = rsim5[b * NI + step];
    dist[n0 + t]       = rs * (f1 / sM) + (1.f - rs) * (e1 / sN);
    dist[n0 + 256 + t] = rs * (f2 / sM) + (1.f - rs) * (e2 / sN);
    msgdot[n0 + t] = 0.f;
    msgdot[n0 + 256 + t] = 0.f;
}

// final aggregation (bf16 attrs)
__global__ __launch_bounds__(320) void final_agg_bf_k(
    const float* __restrict__ psim5, const float* __restrict__ dist,
    const unsigned short* __restrict__ nab, float* __restrict__ agg)
{
    int chunk = blockIdx.x;
    int b = blockIdx.y;
    int h = threadIdx.x;
    if (h >= Hh) return;
    float ps[8];
    #pragma unroll
    for (int p = 0; p < 8; p++) ps[p] = psim5[(b * NI + 4) * 8 + p];
    float acc = 0.f;
    for (int i = 0; i < 32; i++){
        int n = b * NPG + chunk * 32 + i;
        const unsigned short* row = nab + (size_t)n * 2400;
        float wsum = 0.f;
        #pragma unroll
        for (int p = 0; p < 8; p++) wsum += ps[p] * bf2f(row[p * Hh + h]);
        acc += dist[n] * wsum;
    }
    atomicAdd(&agg[b * Hh + h], acc);
}
__global__ __launch_bounds__(320) void final_agg_k(
    const float* __restrict__ psim5, const float* __restrict__ dist,
    const float* __restrict__ na, float* __restrict__ agg)
{
    int chunk = blockIdx.x;
    int b = blockIdx.y;
    int h = threadIdx.x;
    if (h >= Hh) return;
    float ps[8];
    #pragma unroll
    for (int p = 0; p < 8; p++) ps[p] = psim5[(b * NI + 4) * 8 + p];
    float acc = 0.f;
    for (int i = 0; i < 32; i++){
        int n = b * NPG + chunk * 32 + i;
        const float* row = na + (size_t)n * Pp * Hh;
        float wsum = 0.f;
        #pragma unroll
        for (int p = 0; p < 8; p++) wsum += ps[p] * row[p * Hh + h];
        acc += dist[n] * wsum;
    }
    atomicAdd(&agg[b * Hh + h], acc);
}

// fc1 with fused feats (reads enc | agg directly), elu epilogue
__global__ void fc1_k(const float* __restrict__ enc, const float* __restrict__ agg,
                      const float* __restrict__ W, const float* __restrict__ bias,
                      float* __restrict__ z)
{
    int idx = blockIdx.x * 256 + threadIdx.x;
    if (idx >= Bb * 600) return;
    int m = idx / 600, j = idx - m * 600;
    const float* wr = W + (size_t)j * 600;
    float s = 0.f;
    for (int k = 0; k < 300; k++) s += enc[m * 300 + k] * wr[k];
    for (int k = 0; k < 300; k++) s += agg[m * 300 + k] * wr[300 + k];
    z[idx] = eluf(s + bias[j]);
}

__global__ void fc2_k(const float* __restrict__ z, const float* __restrict__ W,
                      const float* __restrict__ bias, float* __restrict__ out)
{
    int idx = blockIdx.x * 256 + threadIdx.x;
    if (idx >= Bb * 1845) return;
    int m = idx / 1845, j = idx - m * 1845;
    const float* wr = W + (size_t)j * 600;
    const float* zr = z + m * 600;
    float s = 0.f;
    for (int k = 0; k < 600; k++) s += zr[k] * wr[k];
    out[idx] = s + bias[j];
}

// ---------------------------------------------------------------------------
extern "C" void kernel_launch(void* const* d_in, const int* in_sizes, int n_in,
                              void* d_out, int out_size, void* d_ws, size_t ws_size,
                              hipStream_t stream)
{
    const float* questions      = (const float*)d_in[0];
    const int*   lengths        = (const int*)  d_in[1];
    const int*   node_indices   = (const int*)  d_in[2];
    const int*   edge_indices   = (const int*)  d_in[3];
    const int*   edge_batch     = (const int*)  d_in[4];
    const float* node_attrs     = (const float*)d_in[5];
    const float* edge_attrs     = (const float*)d_in[6];
    const float* concept_vocab  = (const float*)d_in[7];
    const float* prop_emb       = (const float*)d_in[8];
    const float* tagger_default = (const float*)d_in[9];
    const float* tagger_weight  = (const float*)d_in[10];
    const float* lstm_Wih       = (const float*)d_in[11];
    const float* lstm_Whh       = (const float*)d_in[12];
    const float* lstm_bih       = (const float*)d_in[13];
    const float* lstm_bhh       = (const float*)d_in[14];
    const float* rnn_Wih        = (const float*)d_in[15];
    const float* rnn_Whh        = (const float*)d_in[16];
    const float* rnn_bih        = (const float*)d_in[17];
    const float* rnn_bhh        = (const float*)d_in[18];
    const float* Wnp            = (const float*)d_in[19];
    const float* Wedge          = (const float*)d_in[20];
    const float* w_nscore       = (const float*)d_in[21];
    const float* w_rscore       = (const float*)d_in[22];
    const float* fc1_W          = (const float*)d_in[23];
    const float* fc1_b          = (const float*)d_in[24];
    const float* fc2_W          = (const float*)d_in[25];
    const float* fc2_b          = (const float*)d_in[26];
    float* outf = (float*)d_out;

    float* ws = (float*)d_ws;
    size_t off = 0;
    auto alloc = [&](size_t n){ size_t r = off; off += (n + 63) & ~(size_t)63; return r; };
    size_t o_q2     = alloc(960 * 300);
    size_t o_sim    = alloc((size_t)960 * 2001);
    size_t o_tagged = alloc(960 * 300);
    size_t o_xw     = alloc((size_t)960 * 1200);
    size_t o_enc    = alloc(9600);
    size_t o_hidden = alloc(48000);
    size_t o_instr  = alloc(48000);
    size_t o_psim5  = alloc(1280);
    size_t o_rsim5  = alloc(160);
    size_t o_iscl4  = alloc((size_t)4 * Bb * 2400);
    size_t o_nsc4   = alloc((size_t)4 * Nn);
    size_t o_es4    = alloc((size_t)4 * Ee);
    size_t o_msgdot = alloc(Nn);
    size_t o_dist   = alloc(Nn);
    size_t o_agg    = alloc(9600);
    size_t o_z      = alloc(19200);
    size_t o_btn    = alloc((size_t)304 * 2400 / 2);
    size_t o_bte    = alloc((size_t)304 * 320 / 2);
    size_t o_wn     = alloc(304);
    size_t o_wr     = alloc(304);
    size_t o_wlstm  = alloc(180000);
    size_t o_rwhhT  = alloc(90000);
    size_t o_rwihT  = alloc(90000);
    size_t o_btq    = alloc((size_t)304 * 320 / 2);
    size_t o_btv    = alloc((size_t)2128 * 320 / 2);
    size_t o_btc    = alloc((size_t)304 * 2016 / 2);
    size_t o_btw    = alloc((size_t)1216 * 320 / 2);
    size_t o_nab    = alloc((size_t)Nn * 2400 / 2);
    size_t o_eab    = alloc((size_t)Ee * 320 / 2);
    const bool bigws = ws_size >= off * sizeof(float);

    unsigned short* btn = (unsigned short*)(ws + o_btn);
    unsigned short* bte = (unsigned short*)(ws + o_bte);
    unsigned short* wlstm = (unsigned short*)(ws + o_wlstm);
    unsigned short* btq = (unsigned short*)(ws + o_btq);
    unsigned short* btv = (unsigned short*)(ws + o_btv);
    unsigned short* btc = (unsigned short*)(ws + o_btc);
    unsigned short* btw = (unsigned short*)(ws + o_btw);
    unsigned short* nab = (unsigned short*)(ws + o_nab);
    unsigned short* eab = (unsigned short*)(ws + o_eab);

    // ---- one prep launch (all weight tables) + one convert launch ----
    prep_all_k<<<(R_TOTAL + 255)/256, 256, 0, stream>>>(
        Wnp, Wedge, tagger_weight, concept_vocab, tagger_default,
        lstm_Wih, lstm_Whh, rnn_Whh, rnn_Wih, w_nscore, w_rscore,
        btn, bte, btq, btv, btc, btw, wlstm,
        ws + o_rwhhT, ws + o_rwihT, ws + o_wn, ws + o_wr);
    if (bigws)
        cvt_both_k<<<2048, 256, 0, stream>>>(node_attrs, edge_attrs, nab, eab);

    // ---- tagger chain ----
    mfma_gemm_k<<<dim3(15,1), 256, 0, stream>>>(
        questions, 300, 300, 10, btq, 320, 300, ws + o_q2, 300, nullptr, nullptr);
    mfma_gemm_k<<<dim3(15,7), 256, 0, stream>>>(
        ws + o_q2, 300, 300, 10, btv, 320, 2001, ws + o_sim, 2001, nullptr, nullptr);
    softmax_rows_k<<<960, 256, 0, stream>>>(ws + o_sim, 2001);
    mfma_gemm_k<<<dim3(15,1), 256, 0, stream>>>(
        ws + o_sim, 2001, 2000, 63, btc, 2016, 300, ws + o_tagged, 300,
        ws + o_sim + 2000, questions);

    // ---- LSTM ----
    mfma_gemm_k<<<dim3(15,4), 256, 0, stream>>>(
        ws + o_tagged, 300, 300, 10, btw, 320, 1200, ws + o_xw, 1200, nullptr, nullptr);
    lstm_fast_k<<<Bb, 640, 0, stream>>>(ws + o_xw, wlstm, lstm_bih, lstm_bhh,
                                        lengths, ws + o_enc);

    // ---- RNN + instructions ----
    rnn_all_k<<<Bb, 320, 0, stream>>>(ws + o_enc, ws + o_rwihT, ws + o_rwhhT,
                                      rnn_bih, rnn_bhh, ws + o_hidden);
    scores_instr_k<<<40, 256, 0, stream>>>(ws + o_hidden, ws + o_tagged, lengths, ws + o_instr);

    // ---- hoisted data-parallel phase (batched over steps via blockIdx.y) ----
    prop_softmax_all_k<<<40, 256, 0, stream>>>(ws + o_instr, prop_emb, ws + o_psim5, ws + o_rsim5);
    iscale4_k<<<(4*Bb*2400 + 255)/256, 256, 0, stream>>>(ws + o_instr, ws + o_psim5, ws + o_iscl4);
    if (bigws) {
        mfma_node_k<<<dim3(Nn/64, 4), 256, 0, stream>>>(
            nab, btn, ws + o_iscl4, node_indices, ws + o_wn, ws + o_nsc4);
        mfma_edge_k<<<dim3(Ee/64, 4), 256, 0, stream>>>(
            eab, bte, ws + o_instr, edge_batch, ws + o_wr, ws + o_es4);
    } else {
        mfma_node_f_k<<<dim3(Nn/64, 4), 256, 0, stream>>>(
            node_attrs, btn, ws + o_iscl4, node_indices, ws + o_wn, ws + o_nsc4);
        mfma_edge_f_k<<<dim3(Ee/64, 4), 256, 0, stream>>>(
            edge_attrs, bte, ws + o_instr, edge_batch, ws + o_wr, ws + o_es4);
    }

    // ---- serial message-passing tail ----
    init_k<<<64, 256, 0, stream>>>(ws + o_dist, ws + o_msgdot, ws + o_agg);
    for (int step = 0; step < 4; step++){
        edge_msg_k<<<512, 256, 0, stream>>>(edge_indices, ws + o_es4 + (size_t)step * Ee,
                                            ws + o_dist, ws + o_msgdot);
        seg_update_k<<<32, 256, 0, stream>>>(ws + o_nsc4 + (size_t)step * Nn, ws + o_msgdot,
                                             ws + o_rsim5, step, ws + o_dist);
    }

    // ---- final aggregation + FCs ----
    if (bigws)
        final_agg_bf_k<<<dim3(16,32), 320, 0, stream>>>(ws + o_psim5, ws + o_dist, nab, ws + o_agg);
    else
        final_agg_k<<<dim3(16,32), 320, 0, stream>>>(ws + o_psim5, ws + o_dist, node_attrs, ws + o_agg);
    fc1_k<<<75, 256, 0, stream>>>(ws + o_enc, ws + o_agg, fc1_W, fc1_b, ws + o_z);
    fc2_k<<<(Bb*1845 + 255)/256, 256, 0, stream>>>(ws + o_z, fc2_W, fc2_b, outf);
}